// Round 8
// baseline (204.703 us; speedup 1.0000x reference)
//
#include <hip/hip_runtime.h>

// GraphTransformerBlock2: GATConv(H=3,C=64, edge_dim=5, self-loops w/ mean fill)
// -> linear1 -> LN(x + .) -> linear2 -> LN(lin + .)
// All float32 I/O. edge_index int32 (2,E): src=ei[0:E], dst=ei[E:2E].
//
// R7: revert gather table to R4's 3-plane bf16 xsb (384B/edge, zero pad waste;
//     R6's uint2 pack fetched 512B/edge -> FETCH 140->192MB regression).
//     Keep exp2+log2e folding, 16B payload, no float atomics.
//     Phase B unrolled x4 (4 independent gather+fma chains).

#define HH 3
#define CC 64
#define DIN 64
#define ED 5
#define HC 192
#define NEG_SLOPE 0.2f
#define LN_EPS 1e-5f
#define LOG2E 1.44269504f

typedef __attribute__((ext_vector_type(8))) short bf16x8;
typedef __attribute__((ext_vector_type(4))) float f32x4;

__device__ __forceinline__ float leaky(float l) { return (l >= 0.f) ? l : NEG_SLOPE * l; }

__device__ __forceinline__ unsigned short f2bf(float f) {
    unsigned u = __float_as_uint(f);
    unsigned r = (u + 0x7FFFu + ((u >> 16) & 1u)) >> 16;   // RNE
    return (unsigned short)r;
}
__device__ __forceinline__ float bf2f(unsigned short u) {
    return __uint_as_float((unsigned)u << 16);
}
__device__ __forceinline__ float bf_lo(unsigned v) { return __uint_as_float(v << 16); }
__device__ __forceinline__ float bf_hi(unsigned v) { return __uint_as_float(v & 0xFFFF0000u); }

__device__ __forceinline__ bf16x8 pack8(float4 a, float4 b) {
    bf16x8 r;
    r[0] = (short)f2bf(a.x); r[1] = (short)f2bf(a.y);
    r[2] = (short)f2bf(a.z); r[3] = (short)f2bf(a.w);
    r[4] = (short)f2bf(b.x); r[5] = (short)f2bf(b.y);
    r[6] = (short)f2bf(b.z); r[7] = (short)f2bf(b.w);
    return r;
}

// ---------- prep (bf16 transposed weights + folded bias + we*log2e) + cnt ----------
#define PREP_TOT (HC*DIN + DIN*HC + CC*CC + CC + ED*HH)
#define PREP_BLOCKS 30
__global__ __launch_bounds__(256) void k_prep_cnt(const float* __restrict__ lin_w,
                                                  const float* __restrict__ w1,
                                                  const float* __restrict__ w2,
                                                  const float* __restrict__ b1,
                                                  const float* __restrict__ gat_bias,
                                                  const float* __restrict__ lin_edge_w,
                                                  const float* __restrict__ att_edge,
                                                  unsigned short* __restrict__ linwt,
                                                  unsigned short* __restrict__ w1t,
                                                  unsigned short* __restrict__ w2t,
                                                  float* __restrict__ b1p,
                                                  float* __restrict__ we,
                                                  const int* __restrict__ ei,
                                                  int* __restrict__ icnt, int E) {
    if (blockIdx.x < PREP_BLOCKS) {
        for (int i = blockIdx.x * 256 + threadIdx.x; i < PREP_TOT; i += PREP_BLOCKS * 256) {
            if (i < HC * DIN) {
                int c = i >> 6, k = i & 63;
                linwt[i] = f2bf(lin_w[k * HC + c]);
            } else if (i < 2 * HC * DIN) {
                int j = i - HC * DIN;
                int c = j / HC, k = j - c * HC;
                w1t[j] = f2bf(w1[k * CC + c]);
            } else if (i < 2 * HC * DIN + CC * CC) {
                int j = i - 2 * HC * DIN;
                int c = j >> 6, k = j & 63;
                w2t[j] = f2bf(w2[k * CC + c]);
            } else if (i < 2 * HC * DIN + CC * CC + CC) {
                int c = i - (2 * HC * DIN + CC * CC);
                float s = b1[c];
                for (int k = 0; k < HC; ++k) s += gat_bias[k] * w1[k * CC + c];
                b1p[c] = s;
            } else {
                int q = i - (2 * HC * DIN + CC * CC + CC);
                int d = q / HH, h = q - d * HH;
                float s = 0.f;
                for (int c = 0; c < CC; ++c)
                    s += lin_edge_w[d * HC + h * CC + c] * att_edge[h * CC + c];
                we[q] = s * LOG2E;                     // pre-scale for exp2
            }
        }
    } else {
        int nb = gridDim.x - PREP_BLOCKS;
        for (int e = (blockIdx.x - PREP_BLOCKS) * 256 + threadIdx.x; e < E; e += nb * 256)
            atomicAdd(&icnt[ei[E + e]], 1);
    }
}

// ---------- xs = x @ lin_w (MFMA) -> 3-plane bf16 xsb + a_src/a_dst (pre-scaled) ----------
__global__ __launch_bounds__(256) void k_xs(const float* __restrict__ x,
                                            const unsigned short* __restrict__ linwt,
                                            const float* __restrict__ att_src,
                                            const float* __restrict__ att_dst,
                                            unsigned short* __restrict__ xsb,
                                            float* __restrict__ a_src,
                                            float* __restrict__ a_dst, int N) {
    int lane = threadIdx.x & 63, w = threadIdx.x >> 6;
    int l15 = lane & 15, kg = (lane >> 4) * 8;
    int nb = blockIdx.x * 64;
    int arow = nb + w * 16 + l15;
    int arow_c = min(arow, N - 1);

    f32x4 acc[12];
    #pragma unroll
    for (int ct = 0; ct < 12; ++ct) acc[ct] = (f32x4){0.f, 0.f, 0.f, 0.f};

    #pragma unroll
    for (int k0 = 0; k0 < DIN; k0 += 32) {
        const float* ap = x + (size_t)arow_c * DIN + k0 + kg;
        float4 a0 = *(const float4*)ap;
        float4 a1 = *(const float4*)(ap + 4);
        bf16x8 af = pack8(a0, a1);
        #pragma unroll
        for (int ct = 0; ct < 12; ++ct) {
            bf16x8 bf = *(const bf16x8*)(linwt + (size_t)(ct * 16 + l15) * DIN + k0 + kg);
            acc[ct] = __builtin_amdgcn_mfma_f32_16x16x32_bf16(af, bf, acc[ct], 0, 0, 0);
        }
    }

    float asv[12], adv[12];
    #pragma unroll
    for (int ct = 0; ct < 12; ++ct) {
        int c = ct * 16 + l15;
        asv[ct] = att_src[c]; adv[ct] = att_dst[c];
    }

    int rbase = nb + w * 16 + (lane >> 4) * 4;
    #pragma unroll
    for (int j = 0; j < 4; ++j) {
        int r = rbase + j;
        bool ok = r < N;
        float ps0 = 0.f, ps1 = 0.f, ps2 = 0.f, pd0 = 0.f, pd1 = 0.f, pd2 = 0.f;
        #pragma unroll
        for (int ct = 0; ct < 12; ++ct) {
            float v = acc[ct][j];
            if (ok) xsb[(size_t)r * HC + ct * 16 + l15] = f2bf(v);
            float s = v * asv[ct], d = v * adv[ct];
            if (ct < 4)      { ps0 += s; pd0 += d; }
            else if (ct < 8) { ps1 += s; pd1 += d; }
            else             { ps2 += s; pd2 += d; }
        }
        #pragma unroll
        for (int o = 1; o < 16; o <<= 1) {
            ps0 += __shfl_xor(ps0, o, 64); pd0 += __shfl_xor(pd0, o, 64);
            ps1 += __shfl_xor(ps1, o, 64); pd1 += __shfl_xor(pd1, o, 64);
            ps2 += __shfl_xor(ps2, o, 64); pd2 += __shfl_xor(pd2, o, 64);
        }
        if (ok && l15 == 0) {
            a_src[r * HH + 0] = ps0 * LOG2E; a_src[r * HH + 1] = ps1 * LOG2E;
            a_src[r * HH + 2] = ps2 * LOG2E;
            a_dst[r * HH + 0] = pd0 * LOG2E; a_dst[r * HH + 1] = pd1 * LOG2E;
            a_dst[r * HH + 2] = pd2 * LOG2E;
        }
    }
}

// ---------- multi-block exclusive scan (3 kernels) ----------
__global__ __launch_bounds__(256) void k_scan1(const int* __restrict__ icnt,
                                               int* __restrict__ bsum, int N) {
    int i = blockIdx.x * 256 + threadIdx.x;
    int lane = threadIdx.x & 63, wid = threadIdx.x >> 6;
    int v = (i < N) ? icnt[i] : 0;
    #pragma unroll
    for (int o = 32; o; o >>= 1) v += __shfl_xor(v, o, 64);
    __shared__ int wt[4];
    if (lane == 0) wt[wid] = v;
    __syncthreads();
    if (threadIdx.x == 0) bsum[blockIdx.x] = wt[0] + wt[1] + wt[2] + wt[3];
}

__global__ __launch_bounds__(1024) void k_scan2(const int* __restrict__ bsum,
                                                int* __restrict__ boff, int nb) {
    __shared__ int s[1024];
    int t = threadIdx.x;
    int v = (t < nb) ? bsum[t] : 0;
    s[t] = v;
    __syncthreads();
    for (int d = 1; d < 1024; d <<= 1) {
        int u = (t >= d) ? s[t - d] : 0;
        __syncthreads();
        s[t] += u;
        __syncthreads();
    }
    if (t < nb) boff[t] = s[t] - v;   // exclusive
}

__global__ __launch_bounds__(256) void k_scan3(const int* __restrict__ icnt,
                                               const int* __restrict__ boff,
                                               int* __restrict__ off,
                                               int* __restrict__ cursor, int N) {
    int i = blockIdx.x * 256 + threadIdx.x;
    int lane = threadIdx.x & 63, wid = threadIdx.x >> 6;
    int v = (i < N) ? icnt[i] : 0;
    int incl = v;
    #pragma unroll
    for (int o = 1; o < 64; o <<= 1) {
        int u = __shfl_up(incl, o, 64);
        if (lane >= o) incl += u;
    }
    __shared__ int wt[4];
    if (lane == 63) wt[wid] = incl;
    __syncthreads();
    int wpre = 0;
    for (int w = 0; w < wid; ++w) wpre += wt[w];
    int excl = boff[blockIdx.x] + wpre + incl - v;
    if (i < N) {
        off[i] = excl;
        cursor[i] = excl;
        if (i == N - 1) off[N] = excl + v;
    }
}

// ---------- payload fill (CSR order), 16B/edge, NO float atomics ----------
// pk = { bf(lp0)|bf(lp1)<<16, bf(lp2)|bf(ae0)<<16, bf(ae1)|bf(ae2)<<16, src }
__global__ __launch_bounds__(256) void k_fill(const float* __restrict__ ea,
                                              const int* __restrict__ ei,
                                              const float* __restrict__ a_src,
                                              const float* __restrict__ we,
                                              int* __restrict__ cursor,
                                              uint4* __restrict__ payload, int E) {
    int e = blockIdx.x * blockDim.x + threadIdx.x;
    if (e >= E) return;
    int s = ei[e], d = ei[E + e];
    float attr[ED];
    #pragma unroll
    for (int j = 0; j < ED; ++j) attr[j] = ea[(size_t)e * ED + j];
    float aeh[HH], lp[HH];
    #pragma unroll
    for (int h = 0; h < HH; ++h) {
        float a = 0.f;
        #pragma unroll
        for (int j = 0; j < ED; ++j) a += attr[j] * we[j * HH + h];   // we pre-scaled
        aeh[h] = a;
        lp[h] = a_src[s * HH + h] + a;                                 // both scaled
    }
    int pos = atomicAdd(&cursor[d], 1);
    uint4 pk;
    pk.x = (unsigned)f2bf(lp[0])  | ((unsigned)f2bf(lp[1])  << 16);
    pk.y = (unsigned)f2bf(lp[2])  | ((unsigned)f2bf(aeh[0]) << 16);
    pk.z = (unsigned)f2bf(aeh[1]) | ((unsigned)f2bf(aeh[2]) << 16);
    pk.w = (unsigned)s;
    payload[pos] = pk;
}

// ---------- per-dst softmax + gather: two-phase, 3-plane gather, x4 unroll ----------
__global__ __launch_bounds__(256) void k_gat(const unsigned short* __restrict__ xsb,
                                             const float* __restrict__ a_src,
                                             const float* __restrict__ a_dst,
                                             const int* __restrict__ off,
                                             const uint4* __restrict__ payload,
                                             unsigned short* __restrict__ oaccb, int N) {
    __shared__ float4 wbuf[4][64];
    int lane = threadIdx.x & 63;
    int wid  = threadIdx.x >> 6;
    for (int n = blockIdx.x * 4 + wid; n < N; n += gridDim.x * 4) {
        int beg = off[n], end = off[n + 1];
        int deg = end - beg;
        float ad0 = a_dst[n * HH + 0], ad1 = a_dst[n * HH + 1], ad2 = a_dst[n * HH + 2];
        float pden0 = 0.f, pden1 = 0.f, pden2 = 0.f;     // per-lane partials
        float pae0 = 0.f, pae1 = 0.f, pae2 = 0.f;
        float a0A = 0.f, a1A = 0.f, a2A = 0.f;
        float a0B = 0.f, a1B = 0.f, a2B = 0.f;
        float a0C = 0.f, a1C = 0.f, a2C = 0.f;
        float a0D = 0.f, a1D = 0.f, a2D = 0.f;

        for (int c0 = 0; c0 < deg; c0 += 64) {
            int cn = min(deg - c0, 64);
            // --- phase A: lane = edge ---
            float w0 = 0.f, w1 = 0.f, w2 = 0.f;
            int src = 0;
            if (lane < cn) {
                uint4 p = payload[beg + c0 + lane];
                w0 = exp2f(leaky(bf_lo(p.x) + ad0));
                w1 = exp2f(leaky(bf_hi(p.x) + ad1));
                w2 = exp2f(leaky(bf_lo(p.y) + ad2));
                pae0 += bf_hi(p.y);
                pae1 += bf_lo(p.z);
                pae2 += bf_hi(p.z);
                pden0 += w0; pden1 += w1; pden2 += w2;
                src = (int)p.w;
            }
            wbuf[wid][lane] = make_float4(w0, w1, w2, __int_as_float(src));
            // --- phase B: lane = feature, 3 u16 loads (imm offsets) per edge, x4 ---
            int i = 0;
            for (; i + 4 <= cn; i += 4) {
                float4 ta = wbuf[wid][i];
                float4 tb = wbuf[wid][i + 1];
                float4 tc = wbuf[wid][i + 2];
                float4 td = wbuf[wid][i + 3];
                unsigned sa = (unsigned)__float_as_int(ta.w) * HC + lane;
                unsigned sb = (unsigned)__float_as_int(tb.w) * HC + lane;
                unsigned sc = (unsigned)__float_as_int(tc.w) * HC + lane;
                unsigned sd = (unsigned)__float_as_int(td.w) * HC + lane;
                a0A += ta.x * bf2f(xsb[sa]);
                a1A += ta.y * bf2f(xsb[sa + 64]);
                a2A += ta.z * bf2f(xsb[sa + 128]);
                a0B += tb.x * bf2f(xsb[sb]);
                a1B += tb.y * bf2f(xsb[sb + 64]);
                a2B += tb.z * bf2f(xsb[sb + 128]);
                a0C += tc.x * bf2f(xsb[sc]);
                a1C += tc.y * bf2f(xsb[sc + 64]);
                a2C += tc.z * bf2f(xsb[sc + 128]);
                a0D += td.x * bf2f(xsb[sd]);
                a1D += td.y * bf2f(xsb[sd + 64]);
                a2D += td.z * bf2f(xsb[sd + 128]);
            }
            for (; i < cn; ++i) {
                float4 ta = wbuf[wid][i];
                unsigned sa = (unsigned)__float_as_int(ta.w) * HC + lane;
                a0A += ta.x * bf2f(xsb[sa]);
                a1A += ta.y * bf2f(xsb[sa + 64]);
                a2A += ta.z * bf2f(xsb[sa + 128]);
            }
        }

        // reduce per-lane partials (den, ae)
        #pragma unroll
        for (int o = 32; o; o >>= 1) {
            pden0 += __shfl_xor(pden0, o, 64);
            pden1 += __shfl_xor(pden1, o, 64);
            pden2 += __shfl_xor(pden2, o, 64);
            pae0  += __shfl_xor(pae0, o, 64);
            pae1  += __shfl_xor(pae1, o, 64);
            pae2  += __shfl_xor(pae2, o, 64);
        }

        // self loop (edge attr = mean of incoming, 0 if deg==0); all pre-scaled
        float dc = fmaxf((float)deg, 1.0f);
        float inv_dc = 1.0f / dc;
        float sl0 = leaky(a_src[n * HH + 0] + ad0 + pae0 * inv_dc);
        float sl1 = leaky(a_src[n * HH + 1] + ad1 + pae1 * inv_dc);
        float sl2 = leaky(a_src[n * HH + 2] + ad2 + pae2 * inv_dc);
        float e0 = exp2f(sl0), e1 = exp2f(sl1), e2 = exp2f(sl2);
        unsigned nb_ = (unsigned)n * HC + lane;
        float den0 = pden0 + e0, den1 = pden1 + e1, den2 = pden2 + e2;
        float acc0 = a0A + a0B + a0C + a0D + e0 * bf2f(xsb[nb_]);
        float acc1 = a1A + a1B + a1C + a1D + e1 * bf2f(xsb[nb_ + 64]);
        float acc2 = a2A + a2B + a2C + a2D + e2 * bf2f(xsb[nb_ + 128]);
        size_t nbse = (size_t)n * HC;
        oaccb[nbse + 0 * CC + lane] = f2bf(acc0 / den0);
        oaccb[nbse + 1 * CC + lane] = f2bf(acc1 / den1);
        oaccb[nbse + 2 * CC + lane] = f2bf(acc2 / den2);
    }
}

// ---------- fused MLP: GEMM1 -> LN1 -> GEMM2 -> LN2 (MFMA, in-reg LN) ----------
__global__ __launch_bounds__(256) void k_mlp(const unsigned short* __restrict__ oaccb,
                                             const unsigned short* __restrict__ w1t,
                                             const unsigned short* __restrict__ w2t,
                                             const float* __restrict__ b1p,
                                             const float* __restrict__ x,
                                             const float* __restrict__ g1,
                                             const float* __restrict__ be1,
                                             const float* __restrict__ b2,
                                             const float* __restrict__ g2,
                                             const float* __restrict__ be2,
                                             float* __restrict__ out, int N) {
    __shared__ unsigned short H1[64 * 72];   // [node-in-tile][feature] bf16, pad 72
    int lane = threadIdx.x & 63, w = threadIdx.x >> 6;
    int l15 = lane & 15, kg = (lane >> 4) * 8;
    int nb = blockIdx.x * 64;
    int arow = nb + w * 16 + l15;
    int arow_c = min(arow, N - 1);

    float c_b1[4], c_g1[4], c_be1[4], c_b2[4], c_g2[4], c_be2[4];
    #pragma unroll
    for (int ct = 0; ct < 4; ++ct) {
        int c = ct * 16 + l15;
        c_b1[ct] = b1p[c]; c_g1[ct] = g1[c]; c_be1[ct] = be1[c];
        c_b2[ct] = b2[c];  c_g2[ct] = g2[c]; c_be2[ct] = be2[c];
    }

    // GEMM1: [64 x 192] @ [192 x 64], A read directly as bf16
    f32x4 acc[4];
    #pragma unroll
    for (int ct = 0; ct < 4; ++ct) acc[ct] = (f32x4){0.f, 0.f, 0.f, 0.f};
    #pragma unroll
    for (int k0 = 0; k0 < HC; k0 += 32) {
        bf16x8 af = *(const bf16x8*)(oaccb + (size_t)arow_c * HC + k0 + kg);
        #pragma unroll
        for (int ct = 0; ct < 4; ++ct) {
            bf16x8 bf = *(const bf16x8*)(w1t + (size_t)(ct * 16 + l15) * HC + k0 + kg);
            acc[ct] = __builtin_amdgcn_mfma_f32_16x16x32_bf16(af, bf, acc[ct], 0, 0, 0);
        }
    }

    // epilogue1: y = acc + b1' + x ; LN1 -> h1 (regs + LDS bf16)
    int rbase = nb + w * 16 + (lane >> 4) * 4;
    int rloc0 = w * 16 + (lane >> 4) * 4;
    float h1v[4][4];
    float y[4][4];
    #pragma unroll
    for (int j = 0; j < 4; ++j) {
        int r = min(rbase + j, N - 1);
        #pragma unroll
        for (int ct = 0; ct < 4; ++ct)
            y[ct][j] = acc[ct][j] + c_b1[ct] + x[(size_t)r * DIN + ct * 16 + l15];
    }
    #pragma unroll
    for (int j = 0; j < 4; ++j) {
        float s = y[0][j] + y[1][j] + y[2][j] + y[3][j];
        #pragma unroll
        for (int o = 1; o < 16; o <<= 1) s += __shfl_xor(s, o, 64);
        float m = s * (1.0f / CC);
        float vs = 0.f;
        #pragma unroll
        for (int ct = 0; ct < 4; ++ct) { float d = y[ct][j] - m; vs += d * d; }
        #pragma unroll
        for (int o = 1; o < 16; o <<= 1) vs += __shfl_xor(vs, o, 64);
        float inv = rsqrtf(vs * (1.0f / CC) + LN_EPS);
        #pragma unroll
        for (int ct = 0; ct < 4; ++ct) {
            float h = (y[ct][j] - m) * inv * c_g1[ct] + c_be1[ct];
            h1v[ct][j] = h;
            H1[(rloc0 + j) * 72 + ct * 16 + l15] = f2bf(h);
        }
    }
    __syncthreads();

    // GEMM2: [64 x 64] @ [64 x 64]
    f32x4 acc2[4];
    #pragma unroll
    for (int ct = 0; ct < 4; ++ct) acc2[ct] = (f32x4){0.f, 0.f, 0.f, 0.f};
    #pragma unroll
    for (int k0 = 0; k0 < CC; k0 += 32) {
        bf16x8 af = *(const bf16x8*)&H1[(w * 16 + l15) * 72 + k0 + kg];
        #pragma unroll
        for (int ct = 0; ct < 4; ++ct) {
            bf16x8 bf = *(const bf16x8*)(w2t + (size_t)(ct * 16 + l15) * CC + k0 + kg);
            acc2[ct] = __builtin_amdgcn_mfma_f32_16x16x32_bf16(af, bf, acc2[ct], 0, 0, 0);
        }
    }

    // epilogue2: z = acc2 + b2 + h1 ; LN2 -> out
    #pragma unroll
    for (int j = 0; j < 4; ++j) {
        float z0 = acc2[0][j] + c_b2[0] + h1v[0][j];
        float z1 = acc2[1][j] + c_b2[1] + h1v[1][j];
        float z2 = acc2[2][j] + c_b2[2] + h1v[2][j];
        float z3 = acc2[3][j] + c_b2[3] + h1v[3][j];
        float s = z0 + z1 + z2 + z3;
        #pragma unroll
        for (int o = 1; o < 16; o <<= 1) s += __shfl_xor(s, o, 64);
        float m = s * (1.0f / CC);
        float d0 = z0 - m, d1 = z1 - m, d2 = z2 - m, d3 = z3 - m;
        float vs = d0 * d0 + d1 * d1 + d2 * d2 + d3 * d3;
        #pragma unroll
        for (int o = 1; o < 16; o <<= 1) vs += __shfl_xor(vs, o, 64);
        float inv = rsqrtf(vs * (1.0f / CC) + LN_EPS);
        int r = rbase + j;
        if (r < N) {
            out[(size_t)r * CC + 0 * 16 + l15] = d0 * inv * c_g2[0] + c_be2[0];
            out[(size_t)r * CC + 1 * 16 + l15] = d1 * inv * c_g2[1] + c_be2[1];
            out[(size_t)r * CC + 2 * 16 + l15] = d2 * inv * c_g2[2] + c_be2[2];
            out[(size_t)r * CC + 3 * 16 + l15] = d3 * inv * c_g2[3] + c_be2[3];
        }
    }
}

extern "C" void kernel_launch(void* const* d_in, const int* in_sizes, int n_in,
                              void* d_out, int out_size, void* d_ws, size_t ws_size,
                              hipStream_t stream) {
    const float* x          = (const float*)d_in[0];
    const float* edge_attr  = (const float*)d_in[1];
    const float* lin_w      = (const float*)d_in[2];
    const float* att_src    = (const float*)d_in[3];
    const float* att_dst    = (const float*)d_in[4];
    const float* lin_edge_w = (const float*)d_in[5];
    const float* att_edge   = (const float*)d_in[6];
    const float* gat_bias   = (const float*)d_in[7];
    const float* w1         = (const float*)d_in[8];
    const float* b1         = (const float*)d_in[9];
    const float* ln1_g      = (const float*)d_in[10];
    const float* ln1_b      = (const float*)d_in[11];
    const float* w2         = (const float*)d_in[12];
    const float* b2         = (const float*)d_in[13];
    const float* ln2_g      = (const float*)d_in[14];
    const float* ln2_b      = (const float*)d_in[15];
    const int*   ei         = (const int*)d_in[16];
    float* out = (float*)d_out;

    const int N = in_sizes[0] / DIN;
    const int E = in_sizes[1] / ED;
    const int nb_scan = (N + 255) / 256;

    char* ws = (char*)d_ws;
    size_t off_b = 0;
    auto alloc = [&](size_t bytes) {
        size_t o = off_b;
        off_b = (off_b + bytes + 255) & ~(size_t)255;
        return o;
    };
    // zeroed region first (single memset)
    int* icnt = (int*)(ws + alloc((size_t)N * 4));
    size_t zero_bytes = off_b;
    // fully-overwritten region
    unsigned short* xsb   = (unsigned short*)(ws + alloc((size_t)N * HC * 2));
    unsigned short* oaccb = (unsigned short*)(ws + alloc((size_t)N * HC * 2));
    float*  a_srcb  = (float*)(ws + alloc((size_t)N * HH * 4));
    float*  a_dstb  = (float*)(ws + alloc((size_t)N * HH * 4));
    int*    offb    = (int*)(ws + alloc((size_t)(N + 1) * 4));
    int*    cursor  = (int*)(ws + alloc((size_t)N * 4));
    int*    bsum    = (int*)(ws + alloc((size_t)nb_scan * 4));
    int*    boff    = (int*)(ws + alloc((size_t)nb_scan * 4));
    uint4*  payload = (uint4*)(ws + alloc((size_t)E * 16));
    unsigned short* linwt = (unsigned short*)(ws + alloc((size_t)HC * DIN * 2));
    unsigned short* w1t   = (unsigned short*)(ws + alloc((size_t)DIN * HC * 2));
    unsigned short* w2t   = (unsigned short*)(ws + alloc((size_t)CC * CC * 2));
    float* b1p = (float*)(ws + alloc((size_t)CC * 4));
    float* we  = (float*)(ws + alloc((size_t)ED * HH * 4));
    (void)ws_size; (void)n_in; (void)out_size;

    hipMemsetAsync(d_ws, 0, zero_bytes, stream);

    k_prep_cnt<<<PREP_BLOCKS + (E + 255) / 256, 256, 0, stream>>>(
        lin_w, w1, w2, b1, gat_bias, lin_edge_w, att_edge,
        linwt, w1t, w2t, b1p, we, ei, icnt, E);
    k_xs<<<(N + 63) / 64, 256, 0, stream>>>(x, linwt, att_src, att_dst, xsb, a_srcb, a_dstb, N);
    k_scan1<<<nb_scan, 256, 0, stream>>>(icnt, bsum, N);
    k_scan2<<<1, 1024, 0, stream>>>(bsum, boff, nb_scan);
    k_scan3<<<nb_scan, 256, 0, stream>>>(icnt, boff, offb, cursor, N);
    k_fill<<<(E + 255) / 256, 256, 0, stream>>>(edge_attr, ei, a_srcb, we, cursor,
                                                payload, E);
    k_gat<<<(N + 3) / 4, 256, 0, stream>>>(xsb, a_srcb, a_dstb, offb, payload, oaccb, N);
    k_mlp<<<(N + 63) / 64, 256, 0, stream>>>(oaccb, w1t, w2t, b1p, x,
                                             ln1_g, ln1_b, b2, ln2_g, ln2_b, out, N);
}

// Round 9
// 198.256 us; speedup vs baseline: 1.0325x; 1.0325x over previous
//
#include <hip/hip_runtime.h>

// GraphTransformerBlock2: GATConv(H=3,C=64, edge_dim=5, self-loops w/ mean fill)
// -> linear1 -> LN(x + .) -> linear2 -> LN(lin + .)
// All float32 I/O. edge_index int32 (2,E): src=ei[0:E], dst=ei[E:2E].
//
// R8: k_gat phase-B back to x2 unroll (R7's x4 pushed VGPR 28->44, occupancy
//     68->44% -> net loss). Keep 3-plane zero-waste gather (384B/edge),
//     exp2+log2e folding, 16B payload, no float atomics. Self-loop loads
//     hoisted ahead of the edge loop.

#define HH 3
#define CC 64
#define DIN 64
#define ED 5
#define HC 192
#define NEG_SLOPE 0.2f
#define LN_EPS 1e-5f
#define LOG2E 1.44269504f

typedef __attribute__((ext_vector_type(8))) short bf16x8;
typedef __attribute__((ext_vector_type(4))) float f32x4;

__device__ __forceinline__ float leaky(float l) { return (l >= 0.f) ? l : NEG_SLOPE * l; }

__device__ __forceinline__ unsigned short f2bf(float f) {
    unsigned u = __float_as_uint(f);
    unsigned r = (u + 0x7FFFu + ((u >> 16) & 1u)) >> 16;   // RNE
    return (unsigned short)r;
}
__device__ __forceinline__ float bf2f(unsigned short u) {
    return __uint_as_float((unsigned)u << 16);
}
__device__ __forceinline__ float bf_lo(unsigned v) { return __uint_as_float(v << 16); }
__device__ __forceinline__ float bf_hi(unsigned v) { return __uint_as_float(v & 0xFFFF0000u); }

__device__ __forceinline__ bf16x8 pack8(float4 a, float4 b) {
    bf16x8 r;
    r[0] = (short)f2bf(a.x); r[1] = (short)f2bf(a.y);
    r[2] = (short)f2bf(a.z); r[3] = (short)f2bf(a.w);
    r[4] = (short)f2bf(b.x); r[5] = (short)f2bf(b.y);
    r[6] = (short)f2bf(b.z); r[7] = (short)f2bf(b.w);
    return r;
}

// ---------- prep (bf16 transposed weights + folded bias + we*log2e) + cnt ----------
#define PREP_TOT (HC*DIN + DIN*HC + CC*CC + CC + ED*HH)
#define PREP_BLOCKS 30
__global__ __launch_bounds__(256) void k_prep_cnt(const float* __restrict__ lin_w,
                                                  const float* __restrict__ w1,
                                                  const float* __restrict__ w2,
                                                  const float* __restrict__ b1,
                                                  const float* __restrict__ gat_bias,
                                                  const float* __restrict__ lin_edge_w,
                                                  const float* __restrict__ att_edge,
                                                  unsigned short* __restrict__ linwt,
                                                  unsigned short* __restrict__ w1t,
                                                  unsigned short* __restrict__ w2t,
                                                  float* __restrict__ b1p,
                                                  float* __restrict__ we,
                                                  const int* __restrict__ ei,
                                                  int* __restrict__ icnt, int E) {
    if (blockIdx.x < PREP_BLOCKS) {
        for (int i = blockIdx.x * 256 + threadIdx.x; i < PREP_TOT; i += PREP_BLOCKS * 256) {
            if (i < HC * DIN) {
                int c = i >> 6, k = i & 63;
                linwt[i] = f2bf(lin_w[k * HC + c]);
            } else if (i < 2 * HC * DIN) {
                int j = i - HC * DIN;
                int c = j / HC, k = j - c * HC;
                w1t[j] = f2bf(w1[k * CC + c]);
            } else if (i < 2 * HC * DIN + CC * CC) {
                int j = i - 2 * HC * DIN;
                int c = j >> 6, k = j & 63;
                w2t[j] = f2bf(w2[k * CC + c]);
            } else if (i < 2 * HC * DIN + CC * CC + CC) {
                int c = i - (2 * HC * DIN + CC * CC);
                float s = b1[c];
                for (int k = 0; k < HC; ++k) s += gat_bias[k] * w1[k * CC + c];
                b1p[c] = s;
            } else {
                int q = i - (2 * HC * DIN + CC * CC + CC);
                int d = q / HH, h = q - d * HH;
                float s = 0.f;
                for (int c = 0; c < CC; ++c)
                    s += lin_edge_w[d * HC + h * CC + c] * att_edge[h * CC + c];
                we[q] = s * LOG2E;                     // pre-scale for exp2
            }
        }
    } else {
        int nb = gridDim.x - PREP_BLOCKS;
        for (int e = (blockIdx.x - PREP_BLOCKS) * 256 + threadIdx.x; e < E; e += nb * 256)
            atomicAdd(&icnt[ei[E + e]], 1);
    }
}

// ---------- xs = x @ lin_w (MFMA) -> 3-plane bf16 xsb + a_src/a_dst (pre-scaled) ----------
__global__ __launch_bounds__(256) void k_xs(const float* __restrict__ x,
                                            const unsigned short* __restrict__ linwt,
                                            const float* __restrict__ att_src,
                                            const float* __restrict__ att_dst,
                                            unsigned short* __restrict__ xsb,
                                            float* __restrict__ a_src,
                                            float* __restrict__ a_dst, int N) {
    int lane = threadIdx.x & 63, w = threadIdx.x >> 6;
    int l15 = lane & 15, kg = (lane >> 4) * 8;
    int nb = blockIdx.x * 64;
    int arow = nb + w * 16 + l15;
    int arow_c = min(arow, N - 1);

    f32x4 acc[12];
    #pragma unroll
    for (int ct = 0; ct < 12; ++ct) acc[ct] = (f32x4){0.f, 0.f, 0.f, 0.f};

    #pragma unroll
    for (int k0 = 0; k0 < DIN; k0 += 32) {
        const float* ap = x + (size_t)arow_c * DIN + k0 + kg;
        float4 a0 = *(const float4*)ap;
        float4 a1 = *(const float4*)(ap + 4);
        bf16x8 af = pack8(a0, a1);
        #pragma unroll
        for (int ct = 0; ct < 12; ++ct) {
            bf16x8 bf = *(const bf16x8*)(linwt + (size_t)(ct * 16 + l15) * DIN + k0 + kg);
            acc[ct] = __builtin_amdgcn_mfma_f32_16x16x32_bf16(af, bf, acc[ct], 0, 0, 0);
        }
    }

    float asv[12], adv[12];
    #pragma unroll
    for (int ct = 0; ct < 12; ++ct) {
        int c = ct * 16 + l15;
        asv[ct] = att_src[c]; adv[ct] = att_dst[c];
    }

    int rbase = nb + w * 16 + (lane >> 4) * 4;
    #pragma unroll
    for (int j = 0; j < 4; ++j) {
        int r = rbase + j;
        bool ok = r < N;
        float ps0 = 0.f, ps1 = 0.f, ps2 = 0.f, pd0 = 0.f, pd1 = 0.f, pd2 = 0.f;
        #pragma unroll
        for (int ct = 0; ct < 12; ++ct) {
            float v = acc[ct][j];
            if (ok) xsb[(size_t)r * HC + ct * 16 + l15] = f2bf(v);
            float s = v * asv[ct], d = v * adv[ct];
            if (ct < 4)      { ps0 += s; pd0 += d; }
            else if (ct < 8) { ps1 += s; pd1 += d; }
            else             { ps2 += s; pd2 += d; }
        }
        #pragma unroll
        for (int o = 1; o < 16; o <<= 1) {
            ps0 += __shfl_xor(ps0, o, 64); pd0 += __shfl_xor(pd0, o, 64);
            ps1 += __shfl_xor(ps1, o, 64); pd1 += __shfl_xor(pd1, o, 64);
            ps2 += __shfl_xor(ps2, o, 64); pd2 += __shfl_xor(pd2, o, 64);
        }
        if (ok && l15 == 0) {
            a_src[r * HH + 0] = ps0 * LOG2E; a_src[r * HH + 1] = ps1 * LOG2E;
            a_src[r * HH + 2] = ps2 * LOG2E;
            a_dst[r * HH + 0] = pd0 * LOG2E; a_dst[r * HH + 1] = pd1 * LOG2E;
            a_dst[r * HH + 2] = pd2 * LOG2E;
        }
    }
}

// ---------- multi-block exclusive scan (3 kernels) ----------
__global__ __launch_bounds__(256) void k_scan1(const int* __restrict__ icnt,
                                               int* __restrict__ bsum, int N) {
    int i = blockIdx.x * 256 + threadIdx.x;
    int lane = threadIdx.x & 63, wid = threadIdx.x >> 6;
    int v = (i < N) ? icnt[i] : 0;
    #pragma unroll
    for (int o = 32; o; o >>= 1) v += __shfl_xor(v, o, 64);
    __shared__ int wt[4];
    if (lane == 0) wt[wid] = v;
    __syncthreads();
    if (threadIdx.x == 0) bsum[blockIdx.x] = wt[0] + wt[1] + wt[2] + wt[3];
}

__global__ __launch_bounds__(1024) void k_scan2(const int* __restrict__ bsum,
                                                int* __restrict__ boff, int nb) {
    __shared__ int s[1024];
    int t = threadIdx.x;
    int v = (t < nb) ? bsum[t] : 0;
    s[t] = v;
    __syncthreads();
    for (int d = 1; d < 1024; d <<= 1) {
        int u = (t >= d) ? s[t - d] : 0;
        __syncthreads();
        s[t] += u;
        __syncthreads();
    }
    if (t < nb) boff[t] = s[t] - v;   // exclusive
}

__global__ __launch_bounds__(256) void k_scan3(const int* __restrict__ icnt,
                                               const int* __restrict__ boff,
                                               int* __restrict__ off,
                                               int* __restrict__ cursor, int N) {
    int i = blockIdx.x * 256 + threadIdx.x;
    int lane = threadIdx.x & 63, wid = threadIdx.x >> 6;
    int v = (i < N) ? icnt[i] : 0;
    int incl = v;
    #pragma unroll
    for (int o = 1; o < 64; o <<= 1) {
        int u = __shfl_up(incl, o, 64);
        if (lane >= o) incl += u;
    }
    __shared__ int wt[4];
    if (lane == 63) wt[wid] = incl;
    __syncthreads();
    int wpre = 0;
    for (int w = 0; w < wid; ++w) wpre += wt[w];
    int excl = boff[blockIdx.x] + wpre + incl - v;
    if (i < N) {
        off[i] = excl;
        cursor[i] = excl;
        if (i == N - 1) off[N] = excl + v;
    }
}

// ---------- payload fill (CSR order), 16B/edge, NO float atomics ----------
// pk = { bf(lp0)|bf(lp1)<<16, bf(lp2)|bf(ae0)<<16, bf(ae1)|bf(ae2)<<16, src }
__global__ __launch_bounds__(256) void k_fill(const float* __restrict__ ea,
                                              const int* __restrict__ ei,
                                              const float* __restrict__ a_src,
                                              const float* __restrict__ we,
                                              int* __restrict__ cursor,
                                              uint4* __restrict__ payload, int E) {
    int e = blockIdx.x * blockDim.x + threadIdx.x;
    if (e >= E) return;
    int s = ei[e], d = ei[E + e];
    float attr[ED];
    #pragma unroll
    for (int j = 0; j < ED; ++j) attr[j] = ea[(size_t)e * ED + j];
    float aeh[HH], lp[HH];
    #pragma unroll
    for (int h = 0; h < HH; ++h) {
        float a = 0.f;
        #pragma unroll
        for (int j = 0; j < ED; ++j) a += attr[j] * we[j * HH + h];   // we pre-scaled
        aeh[h] = a;
        lp[h] = a_src[s * HH + h] + a;                                 // both scaled
    }
    int pos = atomicAdd(&cursor[d], 1);
    uint4 pk;
    pk.x = (unsigned)f2bf(lp[0])  | ((unsigned)f2bf(lp[1])  << 16);
    pk.y = (unsigned)f2bf(lp[2])  | ((unsigned)f2bf(aeh[0]) << 16);
    pk.z = (unsigned)f2bf(aeh[1]) | ((unsigned)f2bf(aeh[2]) << 16);
    pk.w = (unsigned)s;
    payload[pos] = pk;
}

// ---------- per-dst softmax + gather: two-phase, 3-plane gather, x2 unroll ----------
__global__ __launch_bounds__(256) void k_gat(const unsigned short* __restrict__ xsb,
                                             const float* __restrict__ a_src,
                                             const float* __restrict__ a_dst,
                                             const int* __restrict__ off,
                                             const uint4* __restrict__ payload,
                                             unsigned short* __restrict__ oaccb, int N) {
    __shared__ float4 wbuf[4][64];
    int lane = threadIdx.x & 63;
    int wid  = threadIdx.x >> 6;
    for (int n = blockIdx.x * 4 + wid; n < N; n += gridDim.x * 4) {
        int beg = off[n], end = off[n + 1];
        int deg = end - beg;
        float ad0 = a_dst[n * HH + 0], ad1 = a_dst[n * HH + 1], ad2 = a_dst[n * HH + 2];
        // hoist self-loop inputs so their latency hides under the edge loop
        float asl0 = a_src[n * HH + 0], asl1 = a_src[n * HH + 1], asl2 = a_src[n * HH + 2];
        unsigned nb_ = (unsigned)n * HC + lane;
        float xn0 = bf2f(xsb[nb_]), xn1 = bf2f(xsb[nb_ + 64]), xn2 = bf2f(xsb[nb_ + 128]);

        float pden0 = 0.f, pden1 = 0.f, pden2 = 0.f;     // per-lane partials
        float pae0 = 0.f, pae1 = 0.f, pae2 = 0.f;
        float a0A = 0.f, a1A = 0.f, a2A = 0.f;
        float a0B = 0.f, a1B = 0.f, a2B = 0.f;

        for (int c0 = 0; c0 < deg; c0 += 64) {
            int cn = min(deg - c0, 64);
            // --- phase A: lane = edge ---
            float w0 = 0.f, w1 = 0.f, w2 = 0.f;
            int src = 0;
            if (lane < cn) {
                uint4 p = payload[beg + c0 + lane];
                w0 = exp2f(leaky(bf_lo(p.x) + ad0));
                w1 = exp2f(leaky(bf_hi(p.x) + ad1));
                w2 = exp2f(leaky(bf_lo(p.y) + ad2));
                pae0 += bf_hi(p.y);
                pae1 += bf_lo(p.z);
                pae2 += bf_hi(p.z);
                pden0 += w0; pden1 += w1; pden2 += w2;
                src = (int)p.w;
            }
            wbuf[wid][lane] = make_float4(w0, w1, w2, __int_as_float(src));
            // --- phase B: lane = feature, 3 u16 loads (imm offsets) per edge, x2 ---
            int i = 0;
            for (; i + 2 <= cn; i += 2) {
                float4 ta = wbuf[wid][i];
                float4 tb = wbuf[wid][i + 1];
                unsigned sa = (unsigned)__float_as_int(ta.w) * HC + lane;
                unsigned sb = (unsigned)__float_as_int(tb.w) * HC + lane;
                a0A += ta.x * bf2f(xsb[sa]);
                a1A += ta.y * bf2f(xsb[sa + 64]);
                a2A += ta.z * bf2f(xsb[sa + 128]);
                a0B += tb.x * bf2f(xsb[sb]);
                a1B += tb.y * bf2f(xsb[sb + 64]);
                a2B += tb.z * bf2f(xsb[sb + 128]);
            }
            if (i < cn) {
                float4 ta = wbuf[wid][i];
                unsigned sa = (unsigned)__float_as_int(ta.w) * HC + lane;
                a0A += ta.x * bf2f(xsb[sa]);
                a1A += ta.y * bf2f(xsb[sa + 64]);
                a2A += ta.z * bf2f(xsb[sa + 128]);
            }
        }

        // reduce per-lane partials (den, ae)
        #pragma unroll
        for (int o = 32; o; o >>= 1) {
            pden0 += __shfl_xor(pden0, o, 64);
            pden1 += __shfl_xor(pden1, o, 64);
            pden2 += __shfl_xor(pden2, o, 64);
            pae0  += __shfl_xor(pae0, o, 64);
            pae1  += __shfl_xor(pae1, o, 64);
            pae2  += __shfl_xor(pae2, o, 64);
        }

        // self loop (edge attr = mean of incoming, 0 if deg==0); all pre-scaled
        float dc = fmaxf((float)deg, 1.0f);
        float inv_dc = 1.0f / dc;
        float sl0 = leaky(asl0 + ad0 + pae0 * inv_dc);
        float sl1 = leaky(asl1 + ad1 + pae1 * inv_dc);
        float sl2 = leaky(asl2 + ad2 + pae2 * inv_dc);
        float e0 = exp2f(sl0), e1 = exp2f(sl1), e2 = exp2f(sl2);
        float den0 = pden0 + e0, den1 = pden1 + e1, den2 = pden2 + e2;
        float acc0 = a0A + a0B + e0 * xn0;
        float acc1 = a1A + a1B + e1 * xn1;
        float acc2 = a2A + a2B + e2 * xn2;
        size_t nbse = (size_t)n * HC;
        oaccb[nbse + 0 * CC + lane] = f2bf(acc0 / den0);
        oaccb[nbse + 1 * CC + lane] = f2bf(acc1 / den1);
        oaccb[nbse + 2 * CC + lane] = f2bf(acc2 / den2);
    }
}

// ---------- fused MLP: GEMM1 -> LN1 -> GEMM2 -> LN2 (MFMA, in-reg LN) ----------
__global__ __launch_bounds__(256) void k_mlp(const unsigned short* __restrict__ oaccb,
                                             const unsigned short* __restrict__ w1t,
                                             const unsigned short* __restrict__ w2t,
                                             const float* __restrict__ b1p,
                                             const float* __restrict__ x,
                                             const float* __restrict__ g1,
                                             const float* __restrict__ be1,
                                             const float* __restrict__ b2,
                                             const float* __restrict__ g2,
                                             const float* __restrict__ be2,
                                             float* __restrict__ out, int N) {
    __shared__ unsigned short H1[64 * 72];   // [node-in-tile][feature] bf16, pad 72
    int lane = threadIdx.x & 63, w = threadIdx.x >> 6;
    int l15 = lane & 15, kg = (lane >> 4) * 8;
    int nb = blockIdx.x * 64;
    int arow = nb + w * 16 + l15;
    int arow_c = min(arow, N - 1);

    float c_b1[4], c_g1[4], c_be1[4], c_b2[4], c_g2[4], c_be2[4];
    #pragma unroll
    for (int ct = 0; ct < 4; ++ct) {
        int c = ct * 16 + l15;
        c_b1[ct] = b1p[c]; c_g1[ct] = g1[c]; c_be1[ct] = be1[c];
        c_b2[ct] = b2[c];  c_g2[ct] = g2[c]; c_be2[ct] = be2[c];
    }

    // GEMM1: [64 x 192] @ [192 x 64], A read directly as bf16
    f32x4 acc[4];
    #pragma unroll
    for (int ct = 0; ct < 4; ++ct) acc[ct] = (f32x4){0.f, 0.f, 0.f, 0.f};
    #pragma unroll
    for (int k0 = 0; k0 < HC; k0 += 32) {
        bf16x8 af = *(const bf16x8*)(oaccb + (size_t)arow_c * HC + k0 + kg);
        #pragma unroll
        for (int ct = 0; ct < 4; ++ct) {
            bf16x8 bf = *(const bf16x8*)(w1t + (size_t)(ct * 16 + l15) * HC + k0 + kg);
            acc[ct] = __builtin_amdgcn_mfma_f32_16x16x32_bf16(af, bf, acc[ct], 0, 0, 0);
        }
    }

    // epilogue1: y = acc + b1' + x ; LN1 -> h1 (regs + LDS bf16)
    int rbase = nb + w * 16 + (lane >> 4) * 4;
    int rloc0 = w * 16 + (lane >> 4) * 4;
    float h1v[4][4];
    float y[4][4];
    #pragma unroll
    for (int j = 0; j < 4; ++j) {
        int r = min(rbase + j, N - 1);
        #pragma unroll
        for (int ct = 0; ct < 4; ++ct)
            y[ct][j] = acc[ct][j] + c_b1[ct] + x[(size_t)r * DIN + ct * 16 + l15];
    }
    #pragma unroll
    for (int j = 0; j < 4; ++j) {
        float s = y[0][j] + y[1][j] + y[2][j] + y[3][j];
        #pragma unroll
        for (int o = 1; o < 16; o <<= 1) s += __shfl_xor(s, o, 64);
        float m = s * (1.0f / CC);
        float vs = 0.f;
        #pragma unroll
        for (int ct = 0; ct < 4; ++ct) { float d = y[ct][j] - m; vs += d * d; }
        #pragma unroll
        for (int o = 1; o < 16; o <<= 1) vs += __shfl_xor(vs, o, 64);
        float inv = rsqrtf(vs * (1.0f / CC) + LN_EPS);
        #pragma unroll
        for (int ct = 0; ct < 4; ++ct) {
            float h = (y[ct][j] - m) * inv * c_g1[ct] + c_be1[ct];
            h1v[ct][j] = h;
            H1[(rloc0 + j) * 72 + ct * 16 + l15] = f2bf(h);
        }
    }
    __syncthreads();

    // GEMM2: [64 x 64] @ [64 x 64]
    f32x4 acc2[4];
    #pragma unroll
    for (int ct = 0; ct < 4; ++ct) acc2[ct] = (f32x4){0.f, 0.f, 0.f, 0.f};
    #pragma unroll
    for (int k0 = 0; k0 < CC; k0 += 32) {
        bf16x8 af = *(const bf16x8*)&H1[(w * 16 + l15) * 72 + k0 + kg];
        #pragma unroll
        for (int ct = 0; ct < 4; ++ct) {
            bf16x8 bf = *(const bf16x8*)(w2t + (size_t)(ct * 16 + l15) * CC + k0 + kg);
            acc2[ct] = __builtin_amdgcn_mfma_f32_16x16x32_bf16(af, bf, acc2[ct], 0, 0, 0);
        }
    }

    // epilogue2: z = acc2 + b2 + h1 ; LN2 -> out
    #pragma unroll
    for (int j = 0; j < 4; ++j) {
        float z0 = acc2[0][j] + c_b2[0] + h1v[0][j];
        float z1 = acc2[1][j] + c_b2[1] + h1v[1][j];
        float z2 = acc2[2][j] + c_b2[2] + h1v[2][j];
        float z3 = acc2[3][j] + c_b2[3] + h1v[3][j];
        float s = z0 + z1 + z2 + z3;
        #pragma unroll
        for (int o = 1; o < 16; o <<= 1) s += __shfl_xor(s, o, 64);
        float m = s * (1.0f / CC);
        float d0 = z0 - m, d1 = z1 - m, d2 = z2 - m, d3 = z3 - m;
        float vs = d0 * d0 + d1 * d1 + d2 * d2 + d3 * d3;
        #pragma unroll
        for (int o = 1; o < 16; o <<= 1) vs += __shfl_xor(vs, o, 64);
        float inv = rsqrtf(vs * (1.0f / CC) + LN_EPS);
        int r = rbase + j;
        if (r < N) {
            out[(size_t)r * CC + 0 * 16 + l15] = d0 * inv * c_g2[0] + c_be2[0];
            out[(size_t)r * CC + 1 * 16 + l15] = d1 * inv * c_g2[1] + c_be2[1];
            out[(size_t)r * CC + 2 * 16 + l15] = d2 * inv * c_g2[2] + c_be2[2];
            out[(size_t)r * CC + 3 * 16 + l15] = d3 * inv * c_g2[3] + c_be2[3];
        }
    }
}

extern "C" void kernel_launch(void* const* d_in, const int* in_sizes, int n_in,
                              void* d_out, int out_size, void* d_ws, size_t ws_size,
                              hipStream_t stream) {
    const float* x          = (const float*)d_in[0];
    const float* edge_attr  = (const float*)d_in[1];
    const float* lin_w      = (const float*)d_in[2];
    const float* att_src    = (const float*)d_in[3];
    const float* att_dst    = (const float*)d_in[4];
    const float* lin_edge_w = (const float*)d_in[5];
    const float* att_edge   = (const float*)d_in[6];
    const float* gat_bias   = (const float*)d_in[7];
    const float* w1         = (const float*)d_in[8];
    const float* b1         = (const float*)d_in[9];
    const float* ln1_g      = (const float*)d_in[10];
    const float* ln1_b      = (const float*)d_in[11];
    const float* w2         = (const float*)d_in[12];
    const float* b2         = (const float*)d_in[13];
    const float* ln2_g      = (const float*)d_in[14];
    const float* ln2_b      = (const float*)d_in[15];
    const int*   ei         = (const int*)d_in[16];
    float* out = (float*)d_out;

    const int N = in_sizes[0] / DIN;
    const int E = in_sizes[1] / ED;
    const int nb_scan = (N + 255) / 256;

    char* ws = (char*)d_ws;
    size_t off_b = 0;
    auto alloc = [&](size_t bytes) {
        size_t o = off_b;
        off_b = (off_b + bytes + 255) & ~(size_t)255;
        return o;
    };
    // zeroed region first (single memset)
    int* icnt = (int*)(ws + alloc((size_t)N * 4));
    size_t zero_bytes = off_b;
    // fully-overwritten region
    unsigned short* xsb   = (unsigned short*)(ws + alloc((size_t)N * HC * 2));
    unsigned short* oaccb = (unsigned short*)(ws + alloc((size_t)N * HC * 2));
    float*  a_srcb  = (float*)(ws + alloc((size_t)N * HH * 4));
    float*  a_dstb  = (float*)(ws + alloc((size_t)N * HH * 4));
    int*    offb    = (int*)(ws + alloc((size_t)(N + 1) * 4));
    int*    cursor  = (int*)(ws + alloc((size_t)N * 4));
    int*    bsum    = (int*)(ws + alloc((size_t)nb_scan * 4));
    int*    boff    = (int*)(ws + alloc((size_t)nb_scan * 4));
    uint4*  payload = (uint4*)(ws + alloc((size_t)E * 16));
    unsigned short* linwt = (unsigned short*)(ws + alloc((size_t)HC * DIN * 2));
    unsigned short* w1t   = (unsigned short*)(ws + alloc((size_t)DIN * HC * 2));
    unsigned short* w2t   = (unsigned short*)(ws + alloc((size_t)CC * CC * 2));
    float* b1p = (float*)(ws + alloc((size_t)CC * 4));
    float* we  = (float*)(ws + alloc((size_t)ED * HH * 4));
    (void)ws_size; (void)n_in; (void)out_size;

    hipMemsetAsync(d_ws, 0, zero_bytes, stream);

    k_prep_cnt<<<PREP_BLOCKS + (E + 255) / 256, 256, 0, stream>>>(
        lin_w, w1, w2, b1, gat_bias, lin_edge_w, att_edge,
        linwt, w1t, w2t, b1p, we, ei, icnt, E);
    k_xs<<<(N + 63) / 64, 256, 0, stream>>>(x, linwt, att_src, att_dst, xsb, a_srcb, a_dstb, N);
    k_scan1<<<nb_scan, 256, 0, stream>>>(icnt, bsum, N);
    k_scan2<<<1, 1024, 0, stream>>>(bsum, boff, nb_scan);
    k_scan3<<<nb_scan, 256, 0, stream>>>(icnt, boff, offb, cursor, N);
    k_fill<<<(E + 255) / 256, 256, 0, stream>>>(edge_attr, ei, a_srcb, we, cursor,
                                                payload, E);
    k_gat<<<(N + 3) / 4, 256, 0, stream>>>(xsb, a_srcb, a_dstb, offb, payload, oaccb, N);
    k_mlp<<<(N + 63) / 64, 256, 0, stream>>>(oaccb, w1t, w2t, b1p, x,
                                             ln1_g, ln1_b, b2, ln2_g, ln2_b, out, N);
}

// Round 10
// 192.062 us; speedup vs baseline: 1.0658x; 1.0322x over previous
//
#include <hip/hip_runtime.h>

// GraphTransformerBlock2: GATConv(H=3,C=64, edge_dim=5, self-loops w/ mean fill)
// -> linear1 -> LN(x + .) -> linear2 -> LN(lin + .)
// All float32 I/O. edge_index int32 (2,E): src=ei[0:E], dst=ei[E:2E].
//
// R9 (k_gat VALU diet, building on R8):
//  - rcp(den) instead of precise f32 div (3x div_scale/fmas/fixup ~45 slots/node -> 6).
//  - a_dst folded into payload logits at k_fill (3 adds/edge saved; a_src/a_dst
//    only touched in epilogue -> loop VGPR down, occupancy up).
//  - xsb row repacked [64 x u32 (h0|h1)][64 x u16 h2]: 2 loads/edge (was 3),
//    __umul24 addressing + lshl_add-derived second index.

#define HH 3
#define CC 64
#define DIN 64
#define ED 5
#define HC 192
#define NEG_SLOPE 0.2f
#define LN_EPS 1e-5f
#define LOG2E 1.44269504f

typedef __attribute__((ext_vector_type(8))) short bf16x8;
typedef __attribute__((ext_vector_type(4))) float f32x4;

__device__ __forceinline__ float leaky(float l) { return fmaxf(l, NEG_SLOPE * l); }

__device__ __forceinline__ unsigned short f2bf(float f) {
    unsigned u = __float_as_uint(f);
    unsigned r = (u + 0x7FFFu + ((u >> 16) & 1u)) >> 16;   // RNE
    return (unsigned short)r;
}
__device__ __forceinline__ float bf2f(unsigned short u) {
    return __uint_as_float((unsigned)u << 16);
}
__device__ __forceinline__ float bf_lo(unsigned v) { return __uint_as_float(v << 16); }
__device__ __forceinline__ float bf_hi(unsigned v) { return __uint_as_float(v & 0xFFFF0000u); }

__device__ __forceinline__ bf16x8 pack8(float4 a, float4 b) {
    bf16x8 r;
    r[0] = (short)f2bf(a.x); r[1] = (short)f2bf(a.y);
    r[2] = (short)f2bf(a.z); r[3] = (short)f2bf(a.w);
    r[4] = (short)f2bf(b.x); r[5] = (short)f2bf(b.y);
    r[6] = (short)f2bf(b.z); r[7] = (short)f2bf(b.w);
    return r;
}

// ---------- prep (bf16 transposed weights + folded bias + we*log2e) + cnt ----------
#define PREP_TOT (HC*DIN + DIN*HC + CC*CC + CC + ED*HH)
#define PREP_BLOCKS 30
__global__ __launch_bounds__(256) void k_prep_cnt(const float* __restrict__ lin_w,
                                                  const float* __restrict__ w1,
                                                  const float* __restrict__ w2,
                                                  const float* __restrict__ b1,
                                                  const float* __restrict__ gat_bias,
                                                  const float* __restrict__ lin_edge_w,
                                                  const float* __restrict__ att_edge,
                                                  unsigned short* __restrict__ linwt,
                                                  unsigned short* __restrict__ w1t,
                                                  unsigned short* __restrict__ w2t,
                                                  float* __restrict__ b1p,
                                                  float* __restrict__ we,
                                                  const int* __restrict__ ei,
                                                  int* __restrict__ icnt, int E) {
    if (blockIdx.x < PREP_BLOCKS) {
        for (int i = blockIdx.x * 256 + threadIdx.x; i < PREP_TOT; i += PREP_BLOCKS * 256) {
            if (i < HC * DIN) {
                int c = i >> 6, k = i & 63;
                linwt[i] = f2bf(lin_w[k * HC + c]);
            } else if (i < 2 * HC * DIN) {
                int j = i - HC * DIN;
                int c = j / HC, k = j - c * HC;
                w1t[j] = f2bf(w1[k * CC + c]);
            } else if (i < 2 * HC * DIN + CC * CC) {
                int j = i - 2 * HC * DIN;
                int c = j >> 6, k = j & 63;
                w2t[j] = f2bf(w2[k * CC + c]);
            } else if (i < 2 * HC * DIN + CC * CC + CC) {
                int c = i - (2 * HC * DIN + CC * CC);
                float s = b1[c];
                for (int k = 0; k < HC; ++k) s += gat_bias[k] * w1[k * CC + c];
                b1p[c] = s;
            } else {
                int q = i - (2 * HC * DIN + CC * CC + CC);
                int d = q / HH, h = q - d * HH;
                float s = 0.f;
                for (int c = 0; c < CC; ++c)
                    s += lin_edge_w[d * HC + h * CC + c] * att_edge[h * CC + c];
                we[q] = s * LOG2E;                     // pre-scale for exp2
            }
        }
    } else {
        int nb = gridDim.x - PREP_BLOCKS;
        for (int e = (blockIdx.x - PREP_BLOCKS) * 256 + threadIdx.x; e < E; e += nb * 256)
            atomicAdd(&icnt[ei[E + e]], 1);
    }
}

// ---------- xs = x @ lin_w (MFMA) -> packed xsb rows + a_src/a_dst (pre-scaled) ----
// xsb row (stride HC u16): u32 word[c] = h0[c]|h1[c]<<16 for c<64; u16[128+c] = h2[c].
__global__ __launch_bounds__(256) void k_xs(const float* __restrict__ x,
                                            const unsigned short* __restrict__ linwt,
                                            const float* __restrict__ att_src,
                                            const float* __restrict__ att_dst,
                                            unsigned short* __restrict__ xsb,
                                            float* __restrict__ a_src,
                                            float* __restrict__ a_dst, int N) {
    int lane = threadIdx.x & 63, w = threadIdx.x >> 6;
    int l15 = lane & 15, kg = (lane >> 4) * 8;
    int nb = blockIdx.x * 64;
    int arow = nb + w * 16 + l15;
    int arow_c = min(arow, N - 1);

    f32x4 acc[12];
    #pragma unroll
    for (int ct = 0; ct < 12; ++ct) acc[ct] = (f32x4){0.f, 0.f, 0.f, 0.f};

    #pragma unroll
    for (int k0 = 0; k0 < DIN; k0 += 32) {
        const float* ap = x + (size_t)arow_c * DIN + k0 + kg;
        float4 a0 = *(const float4*)ap;
        float4 a1 = *(const float4*)(ap + 4);
        bf16x8 af = pack8(a0, a1);
        #pragma unroll
        for (int ct = 0; ct < 12; ++ct) {
            bf16x8 bf = *(const bf16x8*)(linwt + (size_t)(ct * 16 + l15) * DIN + k0 + kg);
            acc[ct] = __builtin_amdgcn_mfma_f32_16x16x32_bf16(af, bf, acc[ct], 0, 0, 0);
        }
    }

    float asv[12], adv[12];
    #pragma unroll
    for (int ct = 0; ct < 12; ++ct) {
        int c = ct * 16 + l15;
        asv[ct] = att_src[c]; adv[ct] = att_dst[c];
    }

    int rbase = nb + w * 16 + (lane >> 4) * 4;
    #pragma unroll
    for (int j = 0; j < 4; ++j) {
        int r = rbase + j;
        bool ok = r < N;
        float ps0 = 0.f, ps1 = 0.f, ps2 = 0.f, pd0 = 0.f, pd1 = 0.f, pd2 = 0.f;
        #pragma unroll
        for (int ct = 0; ct < 12; ++ct) {
            float v = acc[ct][j];
            float s = v * asv[ct], d = v * adv[ct];
            if (ct < 4)      { ps0 += s; pd0 += d; }
            else if (ct < 8) { ps1 += s; pd1 += d; }
            else             { ps2 += s; pd2 += d; }
        }
        if (ok) {
            unsigned* row32 = (unsigned*)(xsb + (size_t)r * HC);
            #pragma unroll
            for (int ct = 0; ct < 4; ++ct) {
                int c = ct * 16 + l15;
                row32[c] = (unsigned)f2bf(acc[ct][j]) | ((unsigned)f2bf(acc[ct + 4][j]) << 16);
                xsb[(size_t)r * HC + 128 + c] = f2bf(acc[ct + 8][j]);
            }
        }
        #pragma unroll
        for (int o = 1; o < 16; o <<= 1) {
            ps0 += __shfl_xor(ps0, o, 64); pd0 += __shfl_xor(pd0, o, 64);
            ps1 += __shfl_xor(ps1, o, 64); pd1 += __shfl_xor(pd1, o, 64);
            ps2 += __shfl_xor(ps2, o, 64); pd2 += __shfl_xor(pd2, o, 64);
        }
        if (ok && l15 == 0) {
            a_src[r * HH + 0] = ps0 * LOG2E; a_src[r * HH + 1] = ps1 * LOG2E;
            a_src[r * HH + 2] = ps2 * LOG2E;
            a_dst[r * HH + 0] = pd0 * LOG2E; a_dst[r * HH + 1] = pd1 * LOG2E;
            a_dst[r * HH + 2] = pd2 * LOG2E;
        }
    }
}

// ---------- multi-block exclusive scan (3 kernels) ----------
__global__ __launch_bounds__(256) void k_scan1(const int* __restrict__ icnt,
                                               int* __restrict__ bsum, int N) {
    int i = blockIdx.x * 256 + threadIdx.x;
    int lane = threadIdx.x & 63, wid = threadIdx.x >> 6;
    int v = (i < N) ? icnt[i] : 0;
    #pragma unroll
    for (int o = 32; o; o >>= 1) v += __shfl_xor(v, o, 64);
    __shared__ int wt[4];
    if (lane == 0) wt[wid] = v;
    __syncthreads();
    if (threadIdx.x == 0) bsum[blockIdx.x] = wt[0] + wt[1] + wt[2] + wt[3];
}

__global__ __launch_bounds__(1024) void k_scan2(const int* __restrict__ bsum,
                                                int* __restrict__ boff, int nb) {
    __shared__ int s[1024];
    int t = threadIdx.x;
    int v = (t < nb) ? bsum[t] : 0;
    s[t] = v;
    __syncthreads();
    for (int d = 1; d < 1024; d <<= 1) {
        int u = (t >= d) ? s[t - d] : 0;
        __syncthreads();
        s[t] += u;
        __syncthreads();
    }
    if (t < nb) boff[t] = s[t] - v;   // exclusive
}

__global__ __launch_bounds__(256) void k_scan3(const int* __restrict__ icnt,
                                               const int* __restrict__ boff,
                                               int* __restrict__ off,
                                               int* __restrict__ cursor, int N) {
    int i = blockIdx.x * 256 + threadIdx.x;
    int lane = threadIdx.x & 63, wid = threadIdx.x >> 6;
    int v = (i < N) ? icnt[i] : 0;
    int incl = v;
    #pragma unroll
    for (int o = 1; o < 64; o <<= 1) {
        int u = __shfl_up(incl, o, 64);
        if (lane >= o) incl += u;
    }
    __shared__ int wt[4];
    if (lane == 63) wt[wid] = incl;
    __syncthreads();
    int wpre = 0;
    for (int w = 0; w < wid; ++w) wpre += wt[w];
    int excl = boff[blockIdx.x] + wpre + incl - v;
    if (i < N) {
        off[i] = excl;
        cursor[i] = excl;
        if (i == N - 1) off[N] = excl + v;
    }
}

// ---------- payload fill (CSR order), 16B/edge, a_dst FOLDED IN ----------
// pk = { bf(lp0)|bf(lp1)<<16, bf(lp2)|bf(ae0)<<16, bf(ae1)|bf(ae2)<<16, src }
// lp[h] = a_src[s][h] + a_dst[d][h] + ae[h]   (complete pre-activation logit)
__global__ __launch_bounds__(256) void k_fill(const float* __restrict__ ea,
                                              const int* __restrict__ ei,
                                              const float* __restrict__ a_src,
                                              const float* __restrict__ a_dst,
                                              const float* __restrict__ we,
                                              int* __restrict__ cursor,
                                              uint4* __restrict__ payload, int E) {
    int e = blockIdx.x * blockDim.x + threadIdx.x;
    if (e >= E) return;
    int s = ei[e], d = ei[E + e];
    float attr[ED];
    #pragma unroll
    for (int j = 0; j < ED; ++j) attr[j] = ea[(size_t)e * ED + j];
    float aeh[HH], lp[HH];
    #pragma unroll
    for (int h = 0; h < HH; ++h) {
        float a = 0.f;
        #pragma unroll
        for (int j = 0; j < ED; ++j) a += attr[j] * we[j * HH + h];   // we pre-scaled
        aeh[h] = a;
        lp[h] = a_src[s * HH + h] + a_dst[d * HH + h] + a;             // all pre-scaled
    }
    int pos = atomicAdd(&cursor[d], 1);
    uint4 pk;
    pk.x = (unsigned)f2bf(lp[0])  | ((unsigned)f2bf(lp[1])  << 16);
    pk.y = (unsigned)f2bf(lp[2])  | ((unsigned)f2bf(aeh[0]) << 16);
    pk.z = (unsigned)f2bf(aeh[1]) | ((unsigned)f2bf(aeh[2]) << 16);
    pk.w = (unsigned)s;
    payload[pos] = pk;
}

// ---------- per-dst softmax + gather: two-phase, 2-load gather, x2 unroll ----------
__global__ __launch_bounds__(256) void k_gat(const unsigned short* __restrict__ xsb,
                                             const float* __restrict__ a_src,
                                             const float* __restrict__ a_dst,
                                             const int* __restrict__ off,
                                             const uint4* __restrict__ payload,
                                             unsigned short* __restrict__ oaccb, int N) {
    __shared__ float4 wbuf[4][64];
    int lane = threadIdx.x & 63;
    int wid  = threadIdx.x >> 6;
    const unsigned* xs32 = (const unsigned*)xsb;
    unsigned c128ml = 128u - (unsigned)lane;            // for (ia<<1)+c128ml = src*192+128+lane
    for (int n = blockIdx.x * 4 + wid; n < N; n += gridDim.x * 4) {
        int beg = off[n], end = off[n + 1];
        int deg = end - beg;

        float pden0 = 0.f, pden1 = 0.f, pden2 = 0.f;     // per-lane partials
        float pae0 = 0.f, pae1 = 0.f, pae2 = 0.f;
        float a0A = 0.f, a1A = 0.f, a2A = 0.f;
        float a0B = 0.f, a1B = 0.f, a2B = 0.f;

        for (int c0 = 0; c0 < deg; c0 += 64) {
            int cn = min(deg - c0, 64);
            // --- phase A: lane = edge (logits are complete; just leaky+exp) ---
            float w0 = 0.f, w1 = 0.f, w2 = 0.f;
            int src = 0;
            if (lane < cn) {
                uint4 p = payload[beg + c0 + lane];
                w0 = exp2f(leaky(bf_lo(p.x)));
                w1 = exp2f(leaky(bf_hi(p.x)));
                w2 = exp2f(leaky(bf_lo(p.y)));
                pae0 += bf_hi(p.y);
                pae1 += bf_lo(p.z);
                pae2 += bf_hi(p.z);
                pden0 += w0; pden1 += w1; pden2 += w2;
                src = (int)p.w;
            }
            wbuf[wid][lane] = make_float4(w0, w1, w2, __int_as_float(src));
            // --- phase B: lane = feature, 2 loads per edge (u32 h0|h1, u16 h2) ---
            int i = 0;
            for (; i + 2 <= cn; i += 2) {
                float4 ta = wbuf[wid][i];
                float4 tb = wbuf[wid][i + 1];
                unsigned ia = __umul24((unsigned)__float_as_int(ta.w), 96u) + lane;
                unsigned ib = __umul24((unsigned)__float_as_int(tb.w), 96u) + lane;
                unsigned va = xs32[ia];
                unsigned vb = xs32[ib];
                float xa2 = bf2f(xsb[(ia << 1) + c128ml]);
                float xb2 = bf2f(xsb[(ib << 1) + c128ml]);
                a0A += ta.x * bf_lo(va); a1A += ta.y * bf_hi(va); a2A += ta.z * xa2;
                a0B += tb.x * bf_lo(vb); a1B += tb.y * bf_hi(vb); a2B += tb.z * xb2;
            }
            if (i < cn) {
                float4 ta = wbuf[wid][i];
                unsigned ia = __umul24((unsigned)__float_as_int(ta.w), 96u) + lane;
                unsigned va = xs32[ia];
                a0A += ta.x * bf_lo(va);
                a1A += ta.y * bf_hi(va);
                a2A += ta.z * bf2f(xsb[(ia << 1) + c128ml]);
            }
        }

        // reduce per-lane partials (den, ae)
        #pragma unroll
        for (int o = 32; o; o >>= 1) {
            pden0 += __shfl_xor(pden0, o, 64);
            pden1 += __shfl_xor(pden1, o, 64);
            pden2 += __shfl_xor(pden2, o, 64);
            pae0  += __shfl_xor(pae0, o, 64);
            pae1  += __shfl_xor(pae1, o, 64);
            pae2  += __shfl_xor(pae2, o, 64);
        }

        // self loop (edge attr = mean of incoming, 0 if deg==0); all pre-scaled
        float dc = fmaxf((float)deg, 1.0f);
        float inv_dc = __builtin_amdgcn_rcpf(dc);
        float sl0 = leaky(a_src[n * HH + 0] + a_dst[n * HH + 0] + pae0 * inv_dc);
        float sl1 = leaky(a_src[n * HH + 1] + a_dst[n * HH + 1] + pae1 * inv_dc);
        float sl2 = leaky(a_src[n * HH + 2] + a_dst[n * HH + 2] + pae2 * inv_dc);
        float e0 = exp2f(sl0), e1 = exp2f(sl1), e2 = exp2f(sl2);
        unsigned ian = __umul24((unsigned)n, 96u) + lane;
        unsigned van = xs32[ian];
        float xn2 = bf2f(xsb[(ian << 1) + c128ml]);
        float r0 = __builtin_amdgcn_rcpf(pden0 + e0);
        float r1 = __builtin_amdgcn_rcpf(pden1 + e1);
        float r2 = __builtin_amdgcn_rcpf(pden2 + e2);
        float acc0 = (a0A + a0B + e0 * bf_lo(van)) * r0;
        float acc1 = (a1A + a1B + e1 * bf_hi(van)) * r1;
        float acc2 = (a2A + a2B + e2 * xn2) * r2;
        size_t nbse = (size_t)n * HC;
        oaccb[nbse + 0 * CC + lane] = f2bf(acc0);
        oaccb[nbse + 1 * CC + lane] = f2bf(acc1);
        oaccb[nbse + 2 * CC + lane] = f2bf(acc2);
    }
}

// ---------- fused MLP: GEMM1 -> LN1 -> GEMM2 -> LN2 (MFMA, in-reg LN) ----------
__global__ __launch_bounds__(256) void k_mlp(const unsigned short* __restrict__ oaccb,
                                             const unsigned short* __restrict__ w1t,
                                             const unsigned short* __restrict__ w2t,
                                             const float* __restrict__ b1p,
                                             const float* __restrict__ x,
                                             const float* __restrict__ g1,
                                             const float* __restrict__ be1,
                                             const float* __restrict__ b2,
                                             const float* __restrict__ g2,
                                             const float* __restrict__ be2,
                                             float* __restrict__ out, int N) {
    __shared__ unsigned short H1[64 * 72];   // [node-in-tile][feature] bf16, pad 72
    int lane = threadIdx.x & 63, w = threadIdx.x >> 6;
    int l15 = lane & 15, kg = (lane >> 4) * 8;
    int nb = blockIdx.x * 64;
    int arow = nb + w * 16 + l15;
    int arow_c = min(arow, N - 1);

    float c_b1[4], c_g1[4], c_be1[4], c_b2[4], c_g2[4], c_be2[4];
    #pragma unroll
    for (int ct = 0; ct < 4; ++ct) {
        int c = ct * 16 + l15;
        c_b1[ct] = b1p[c]; c_g1[ct] = g1[c]; c_be1[ct] = be1[c];
        c_b2[ct] = b2[c];  c_g2[ct] = g2[c]; c_be2[ct] = be2[c];
    }

    // GEMM1: [64 x 192] @ [192 x 64], A read directly as bf16
    f32x4 acc[4];
    #pragma unroll
    for (int ct = 0; ct < 4; ++ct) acc[ct] = (f32x4){0.f, 0.f, 0.f, 0.f};
    #pragma unroll
    for (int k0 = 0; k0 < HC; k0 += 32) {
        bf16x8 af = *(const bf16x8*)(oaccb + (size_t)arow_c * HC + k0 + kg);
        #pragma unroll
        for (int ct = 0; ct < 4; ++ct) {
            bf16x8 bf = *(const bf16x8*)(w1t + (size_t)(ct * 16 + l15) * HC + k0 + kg);
            acc[ct] = __builtin_amdgcn_mfma_f32_16x16x32_bf16(af, bf, acc[ct], 0, 0, 0);
        }
    }

    // epilogue1: y = acc + b1' + x ; LN1 -> h1 (regs + LDS bf16)
    int rbase = nb + w * 16 + (lane >> 4) * 4;
    int rloc0 = w * 16 + (lane >> 4) * 4;
    float h1v[4][4];
    float y[4][4];
    #pragma unroll
    for (int j = 0; j < 4; ++j) {
        int r = min(rbase + j, N - 1);
        #pragma unroll
        for (int ct = 0; ct < 4; ++ct)
            y[ct][j] = acc[ct][j] + c_b1[ct] + x[(size_t)r * DIN + ct * 16 + l15];
    }
    #pragma unroll
    for (int j = 0; j < 4; ++j) {
        float s = y[0][j] + y[1][j] + y[2][j] + y[3][j];
        #pragma unroll
        for (int o = 1; o < 16; o <<= 1) s += __shfl_xor(s, o, 64);
        float m = s * (1.0f / CC);
        float vs = 0.f;
        #pragma unroll
        for (int ct = 0; ct < 4; ++ct) { float d = y[ct][j] - m; vs += d * d; }
        #pragma unroll
        for (int o = 1; o < 16; o <<= 1) vs += __shfl_xor(vs, o, 64);
        float inv = rsqrtf(vs * (1.0f / CC) + LN_EPS);
        #pragma unroll
        for (int ct = 0; ct < 4; ++ct) {
            float h = (y[ct][j] - m) * inv * c_g1[ct] + c_be1[ct];
            h1v[ct][j] = h;
            H1[(rloc0 + j) * 72 + ct * 16 + l15] = f2bf(h);
        }
    }
    __syncthreads();

    // GEMM2: [64 x 64] @ [64 x 64]
    f32x4 acc2[4];
    #pragma unroll
    for (int ct = 0; ct < 4; ++ct) acc2[ct] = (f32x4){0.f, 0.f, 0.f, 0.f};
    #pragma unroll
    for (int k0 = 0; k0 < CC; k0 += 32) {
        bf16x8 af = *(const bf16x8*)&H1[(w * 16 + l15) * 72 + k0 + kg];
        #pragma unroll
        for (int ct = 0; ct < 4; ++ct) {
            bf16x8 bf = *(const bf16x8*)(w2t + (size_t)(ct * 16 + l15) * CC + k0 + kg);
            acc2[ct] = __builtin_amdgcn_mfma_f32_16x16x32_bf16(af, bf, acc2[ct], 0, 0, 0);
        }
    }

    // epilogue2: z = acc2 + b2 + h1 ; LN2 -> out
    #pragma unroll
    for (int j = 0; j < 4; ++j) {
        float z0 = acc2[0][j] + c_b2[0] + h1v[0][j];
        float z1 = acc2[1][j] + c_b2[1] + h1v[1][j];
        float z2 = acc2[2][j] + c_b2[2] + h1v[2][j];
        float z3 = acc2[3][j] + c_b2[3] + h1v[3][j];
        float s = z0 + z1 + z2 + z3;
        #pragma unroll
        for (int o = 1; o < 16; o <<= 1) s += __shfl_xor(s, o, 64);
        float m = s * (1.0f / CC);
        float d0 = z0 - m, d1 = z1 - m, d2 = z2 - m, d3 = z3 - m;
        float vs = d0 * d0 + d1 * d1 + d2 * d2 + d3 * d3;
        #pragma unroll
        for (int o = 1; o < 16; o <<= 1) vs += __shfl_xor(vs, o, 64);
        float inv = rsqrtf(vs * (1.0f / CC) + LN_EPS);
        int r = rbase + j;
        if (r < N) {
            out[(size_t)r * CC + 0 * 16 + l15] = d0 * inv * c_g2[0] + c_be2[0];
            out[(size_t)r * CC + 1 * 16 + l15] = d1 * inv * c_g2[1] + c_be2[1];
            out[(size_t)r * CC + 2 * 16 + l15] = d2 * inv * c_g2[2] + c_be2[2];
            out[(size_t)r * CC + 3 * 16 + l15] = d3 * inv * c_g2[3] + c_be2[3];
        }
    }
}

extern "C" void kernel_launch(void* const* d_in, const int* in_sizes, int n_in,
                              void* d_out, int out_size, void* d_ws, size_t ws_size,
                              hipStream_t stream) {
    const float* x          = (const float*)d_in[0];
    const float* edge_attr  = (const float*)d_in[1];
    const float* lin_w      = (const float*)d_in[2];
    const float* att_src    = (const float*)d_in[3];
    const float* att_dst    = (const float*)d_in[4];
    const float* lin_edge_w = (const float*)d_in[5];
    const float* att_edge   = (const float*)d_in[6];
    const float* gat_bias   = (const float*)d_in[7];
    const float* w1         = (const float*)d_in[8];
    const float* b1         = (const float*)d_in[9];
    const float* ln1_g      = (const float*)d_in[10];
    const float* ln1_b      = (const float*)d_in[11];
    const float* w2         = (const float*)d_in[12];
    const float* b2         = (const float*)d_in[13];
    const float* ln2_g      = (const float*)d_in[14];
    const float* ln2_b      = (const float*)d_in[15];
    const int*   ei         = (const int*)d_in[16];
    float* out = (float*)d_out;

    const int N = in_sizes[0] / DIN;
    const int E = in_sizes[1] / ED;
    const int nb_scan = (N + 255) / 256;

    char* ws = (char*)d_ws;
    size_t off_b = 0;
    auto alloc = [&](size_t bytes) {
        size_t o = off_b;
        off_b = (off_b + bytes + 255) & ~(size_t)255;
        return o;
    };
    // zeroed region first (single memset)
    int* icnt = (int*)(ws + alloc((size_t)N * 4));
    size_t zero_bytes = off_b;
    // fully-overwritten region
    unsigned short* xsb   = (unsigned short*)(ws + alloc((size_t)N * HC * 2));
    unsigned short* oaccb = (unsigned short*)(ws + alloc((size_t)N * HC * 2));
    float*  a_srcb  = (float*)(ws + alloc((size_t)N * HH * 4));
    float*  a_dstb  = (float*)(ws + alloc((size_t)N * HH * 4));
    int*    offb    = (int*)(ws + alloc((size_t)(N + 1) * 4));
    int*    cursor  = (int*)(ws + alloc((size_t)N * 4));
    int*    bsum    = (int*)(ws + alloc((size_t)nb_scan * 4));
    int*    boff    = (int*)(ws + alloc((size_t)nb_scan * 4));
    uint4*  payload = (uint4*)(ws + alloc((size_t)E * 16));
    unsigned short* linwt = (unsigned short*)(ws + alloc((size_t)HC * DIN * 2));
    unsigned short* w1t   = (unsigned short*)(ws + alloc((size_t)DIN * HC * 2));
    unsigned short* w2t   = (unsigned short*)(ws + alloc((size_t)CC * CC * 2));
    float* b1p = (float*)(ws + alloc((size_t)CC * 4));
    float* we  = (float*)(ws + alloc((size_t)ED * HH * 4));
    (void)ws_size; (void)n_in; (void)out_size;

    hipMemsetAsync(d_ws, 0, zero_bytes, stream);

    k_prep_cnt<<<PREP_BLOCKS + (E + 255) / 256, 256, 0, stream>>>(
        lin_w, w1, w2, b1, gat_bias, lin_edge_w, att_edge,
        linwt, w1t, w2t, b1p, we, ei, icnt, E);
    k_xs<<<(N + 63) / 64, 256, 0, stream>>>(x, linwt, att_src, att_dst, xsb, a_srcb, a_dstb, N);
    k_scan1<<<nb_scan, 256, 0, stream>>>(icnt, bsum, N);
    k_scan2<<<1, 1024, 0, stream>>>(bsum, boff, nb_scan);
    k_scan3<<<nb_scan, 256, 0, stream>>>(icnt, boff, offb, cursor, N);
    k_fill<<<(E + 255) / 256, 256, 0, stream>>>(edge_attr, ei, a_srcb, a_dstb, we, cursor,
                                                payload, E);
    k_gat<<<(N + 3) / 4, 256, 0, stream>>>(xsb, a_srcb, a_dstb, offb, payload, oaccb, N);
    k_mlp<<<(N + 63) / 64, 256, 0, stream>>>(oaccb, w1t, w2t, b1p, x,
                                             ln1_g, ln1_b, b2, ln2_g, ln2_b, out, N);
}

// Round 11
// 186.860 us; speedup vs baseline: 1.0955x; 1.0278x over previous
//
#include <hip/hip_runtime.h>

// GraphTransformerBlock2: GATConv(H=3,C=64, edge_dim=5, self-loops w/ mean fill)
// -> linear1 -> LN(x + .) -> linear2 -> LN(lin + .)
// All float32 I/O. edge_index int32 (2,E): src=ei[0:E], dst=ei[E:2E].
//
// R10 (building on R9):
//  - k_gat phase B: wbuf LDS round-trip replaced by v_readlane broadcast of
//    phase-A registers (loop index is wave-uniform -> SGPR). LDS usage -> 0,
//    ds_read latency off the gather critical path.
//  - 3-kernel scan -> 1 kernel: block base via atomicAdd(gtotal, block_sum).
//    CSR need not be monotone; k_gat takes deg from icnt[n].

#define HH 3
#define CC 64
#define DIN 64
#define ED 5
#define HC 192
#define NEG_SLOPE 0.2f
#define LN_EPS 1e-5f
#define LOG2E 1.44269504f

typedef __attribute__((ext_vector_type(8))) short bf16x8;
typedef __attribute__((ext_vector_type(4))) float f32x4;

__device__ __forceinline__ float leaky(float l) { return fmaxf(l, NEG_SLOPE * l); }

__device__ __forceinline__ unsigned short f2bf(float f) {
    unsigned u = __float_as_uint(f);
    unsigned r = (u + 0x7FFFu + ((u >> 16) & 1u)) >> 16;   // RNE
    return (unsigned short)r;
}
__device__ __forceinline__ float bf2f(unsigned short u) {
    return __uint_as_float((unsigned)u << 16);
}
__device__ __forceinline__ float bf_lo(unsigned v) { return __uint_as_float(v << 16); }
__device__ __forceinline__ float bf_hi(unsigned v) { return __uint_as_float(v & 0xFFFF0000u); }
__device__ __forceinline__ float rdl_f(float v, int i) {
    return __int_as_float(__builtin_amdgcn_readlane(__float_as_int(v), i));
}

__device__ __forceinline__ bf16x8 pack8(float4 a, float4 b) {
    bf16x8 r;
    r[0] = (short)f2bf(a.x); r[1] = (short)f2bf(a.y);
    r[2] = (short)f2bf(a.z); r[3] = (short)f2bf(a.w);
    r[4] = (short)f2bf(b.x); r[5] = (short)f2bf(b.y);
    r[6] = (short)f2bf(b.z); r[7] = (short)f2bf(b.w);
    return r;
}

// ---------- prep (bf16 transposed weights + folded bias + we*log2e) + cnt ----------
#define PREP_TOT (HC*DIN + DIN*HC + CC*CC + CC + ED*HH)
#define PREP_BLOCKS 30
__global__ __launch_bounds__(256) void k_prep_cnt(const float* __restrict__ lin_w,
                                                  const float* __restrict__ w1,
                                                  const float* __restrict__ w2,
                                                  const float* __restrict__ b1,
                                                  const float* __restrict__ gat_bias,
                                                  const float* __restrict__ lin_edge_w,
                                                  const float* __restrict__ att_edge,
                                                  unsigned short* __restrict__ linwt,
                                                  unsigned short* __restrict__ w1t,
                                                  unsigned short* __restrict__ w2t,
                                                  float* __restrict__ b1p,
                                                  float* __restrict__ we,
                                                  const int* __restrict__ ei,
                                                  int* __restrict__ icnt, int E) {
    if (blockIdx.x < PREP_BLOCKS) {
        for (int i = blockIdx.x * 256 + threadIdx.x; i < PREP_TOT; i += PREP_BLOCKS * 256) {
            if (i < HC * DIN) {
                int c = i >> 6, k = i & 63;
                linwt[i] = f2bf(lin_w[k * HC + c]);
            } else if (i < 2 * HC * DIN) {
                int j = i - HC * DIN;
                int c = j / HC, k = j - c * HC;
                w1t[j] = f2bf(w1[k * CC + c]);
            } else if (i < 2 * HC * DIN + CC * CC) {
                int j = i - 2 * HC * DIN;
                int c = j >> 6, k = j & 63;
                w2t[j] = f2bf(w2[k * CC + c]);
            } else if (i < 2 * HC * DIN + CC * CC + CC) {
                int c = i - (2 * HC * DIN + CC * CC);
                float s = b1[c];
                for (int k = 0; k < HC; ++k) s += gat_bias[k] * w1[k * CC + c];
                b1p[c] = s;
            } else {
                int q = i - (2 * HC * DIN + CC * CC + CC);
                int d = q / HH, h = q - d * HH;
                float s = 0.f;
                for (int c = 0; c < CC; ++c)
                    s += lin_edge_w[d * HC + h * CC + c] * att_edge[h * CC + c];
                we[q] = s * LOG2E;                     // pre-scale for exp2
            }
        }
    } else {
        int nb = gridDim.x - PREP_BLOCKS;
        for (int e = (blockIdx.x - PREP_BLOCKS) * 256 + threadIdx.x; e < E; e += nb * 256)
            atomicAdd(&icnt[ei[E + e]], 1);
    }
}

// ---------- xs = x @ lin_w (MFMA) -> packed xsb rows + a_src/a_dst (pre-scaled) ----
// xsb row (stride HC u16): u32 word[c] = h0[c]|h1[c]<<16 for c<64; u16[128+c] = h2[c].
__global__ __launch_bounds__(256) void k_xs(const float* __restrict__ x,
                                            const unsigned short* __restrict__ linwt,
                                            const float* __restrict__ att_src,
                                            const float* __restrict__ att_dst,
                                            unsigned short* __restrict__ xsb,
                                            float* __restrict__ a_src,
                                            float* __restrict__ a_dst, int N) {
    int lane = threadIdx.x & 63, w = threadIdx.x >> 6;
    int l15 = lane & 15, kg = (lane >> 4) * 8;
    int nb = blockIdx.x * 64;
    int arow = nb + w * 16 + l15;
    int arow_c = min(arow, N - 1);

    f32x4 acc[12];
    #pragma unroll
    for (int ct = 0; ct < 12; ++ct) acc[ct] = (f32x4){0.f, 0.f, 0.f, 0.f};

    #pragma unroll
    for (int k0 = 0; k0 < DIN; k0 += 32) {
        const float* ap = x + (size_t)arow_c * DIN + k0 + kg;
        float4 a0 = *(const float4*)ap;
        float4 a1 = *(const float4*)(ap + 4);
        bf16x8 af = pack8(a0, a1);
        #pragma unroll
        for (int ct = 0; ct < 12; ++ct) {
            bf16x8 bf = *(const bf16x8*)(linwt + (size_t)(ct * 16 + l15) * DIN + k0 + kg);
            acc[ct] = __builtin_amdgcn_mfma_f32_16x16x32_bf16(af, bf, acc[ct], 0, 0, 0);
        }
    }

    float asv[12], adv[12];
    #pragma unroll
    for (int ct = 0; ct < 12; ++ct) {
        int c = ct * 16 + l15;
        asv[ct] = att_src[c]; adv[ct] = att_dst[c];
    }

    int rbase = nb + w * 16 + (lane >> 4) * 4;
    #pragma unroll
    for (int j = 0; j < 4; ++j) {
        int r = rbase + j;
        bool ok = r < N;
        float ps0 = 0.f, ps1 = 0.f, ps2 = 0.f, pd0 = 0.f, pd1 = 0.f, pd2 = 0.f;
        #pragma unroll
        for (int ct = 0; ct < 12; ++ct) {
            float v = acc[ct][j];
            float s = v * asv[ct], d = v * adv[ct];
            if (ct < 4)      { ps0 += s; pd0 += d; }
            else if (ct < 8) { ps1 += s; pd1 += d; }
            else             { ps2 += s; pd2 += d; }
        }
        if (ok) {
            unsigned* row32 = (unsigned*)(xsb + (size_t)r * HC);
            #pragma unroll
            for (int ct = 0; ct < 4; ++ct) {
                int c = ct * 16 + l15;
                row32[c] = (unsigned)f2bf(acc[ct][j]) | ((unsigned)f2bf(acc[ct + 4][j]) << 16);
                xsb[(size_t)r * HC + 128 + c] = f2bf(acc[ct + 8][j]);
            }
        }
        #pragma unroll
        for (int o = 1; o < 16; o <<= 1) {
            ps0 += __shfl_xor(ps0, o, 64); pd0 += __shfl_xor(pd0, o, 64);
            ps1 += __shfl_xor(ps1, o, 64); pd1 += __shfl_xor(pd1, o, 64);
            ps2 += __shfl_xor(ps2, o, 64); pd2 += __shfl_xor(pd2, o, 64);
        }
        if (ok && l15 == 0) {
            a_src[r * HH + 0] = ps0 * LOG2E; a_src[r * HH + 1] = ps1 * LOG2E;
            a_src[r * HH + 2] = ps2 * LOG2E;
            a_dst[r * HH + 0] = pd0 * LOG2E; a_dst[r * HH + 1] = pd1 * LOG2E;
            a_dst[r * HH + 2] = pd2 * LOG2E;
        }
    }
}

// ---------- single-kernel allocation scan: block base via global atomic ----------
// off[] need not be monotone in n: each node just owns [off[n], off[n]+icnt[n]).
__global__ __launch_bounds__(256) void k_scanA(const int* __restrict__ icnt,
                                               int* __restrict__ gtot,
                                               int* __restrict__ off,
                                               int* __restrict__ cursor, int N) {
    int i = blockIdx.x * 256 + threadIdx.x;
    int lane = threadIdx.x & 63, wid = threadIdx.x >> 6;
    int v = (i < N) ? icnt[i] : 0;
    int incl = v;
    #pragma unroll
    for (int o = 1; o < 64; o <<= 1) {
        int u = __shfl_up(incl, o, 64);
        if (lane >= o) incl += u;
    }
    __shared__ int wt[4];
    __shared__ int base_sh;
    if (lane == 63) wt[wid] = incl;
    __syncthreads();
    if (threadIdx.x == 0)
        base_sh = atomicAdd(gtot, wt[0] + wt[1] + wt[2] + wt[3]);
    __syncthreads();
    int wpre = 0;
    for (int w = 0; w < wid; ++w) wpre += wt[w];
    int excl = base_sh + wpre + incl - v;
    if (i < N) {
        off[i] = excl;
        cursor[i] = excl;
    }
}

// ---------- payload fill (CSR order), 16B/edge, a_dst FOLDED IN ----------
// pk = { bf(lp0)|bf(lp1)<<16, bf(lp2)|bf(ae0)<<16, bf(ae1)|bf(ae2)<<16, src }
__global__ __launch_bounds__(256) void k_fill(const float* __restrict__ ea,
                                              const int* __restrict__ ei,
                                              const float* __restrict__ a_src,
                                              const float* __restrict__ a_dst,
                                              const float* __restrict__ we,
                                              int* __restrict__ cursor,
                                              uint4* __restrict__ payload, int E) {
    int e = blockIdx.x * blockDim.x + threadIdx.x;
    if (e >= E) return;
    int s = ei[e], d = ei[E + e];
    float attr[ED];
    #pragma unroll
    for (int j = 0; j < ED; ++j) attr[j] = ea[(size_t)e * ED + j];
    float aeh[HH], lp[HH];
    #pragma unroll
    for (int h = 0; h < HH; ++h) {
        float a = 0.f;
        #pragma unroll
        for (int j = 0; j < ED; ++j) a += attr[j] * we[j * HH + h];   // we pre-scaled
        aeh[h] = a;
        lp[h] = a_src[s * HH + h] + a_dst[d * HH + h] + a;             // all pre-scaled
    }
    int pos = atomicAdd(&cursor[d], 1);
    uint4 pk;
    pk.x = (unsigned)f2bf(lp[0])  | ((unsigned)f2bf(lp[1])  << 16);
    pk.y = (unsigned)f2bf(lp[2])  | ((unsigned)f2bf(aeh[0]) << 16);
    pk.z = (unsigned)f2bf(aeh[1]) | ((unsigned)f2bf(aeh[2]) << 16);
    pk.w = (unsigned)s;
    payload[pos] = pk;
}

// ---------- per-dst softmax + gather: readlane broadcast, no LDS ----------
__global__ __launch_bounds__(256) void k_gat(const unsigned short* __restrict__ xsb,
                                             const float* __restrict__ a_src,
                                             const float* __restrict__ a_dst,
                                             const int* __restrict__ off,
                                             const int* __restrict__ icnt,
                                             const uint4* __restrict__ payload,
                                             unsigned short* __restrict__ oaccb, int N) {
    int lane = threadIdx.x & 63;
    int wid  = threadIdx.x >> 6;
    const unsigned* xs32 = (const unsigned*)xsb;
    unsigned c128ml = 128u - (unsigned)lane;            // (ia<<1)+c128ml = src*192+128+lane
    for (int n = blockIdx.x * 4 + wid; n < N; n += gridDim.x * 4) {
        int beg = off[n];
        int deg = icnt[n];

        float pden0 = 0.f, pden1 = 0.f, pden2 = 0.f;     // per-lane partials
        float pae0 = 0.f, pae1 = 0.f, pae2 = 0.f;
        float a0A = 0.f, a1A = 0.f, a2A = 0.f;
        float a0B = 0.f, a1B = 0.f, a2B = 0.f;

        for (int c0 = 0; c0 < deg; c0 += 64) {
            int cn = min(deg - c0, 64);
            // --- phase A: lane = edge (registers kept live for phase B) ---
            float w0 = 0.f, w1 = 0.f, w2 = 0.f;
            int srcv = 0;
            if (lane < cn) {
                uint4 p = payload[beg + c0 + lane];
                w0 = exp2f(leaky(bf_lo(p.x)));
                w1 = exp2f(leaky(bf_hi(p.x)));
                w2 = exp2f(leaky(bf_lo(p.y)));
                pae0 += bf_hi(p.y);
                pae1 += bf_lo(p.z);
                pae2 += bf_hi(p.z);
                pden0 += w0; pden1 += w1; pden2 += w2;
                srcv = (int)p.w;
            }
            // --- phase B: lane = feature; per-edge scalars via readlane (SGPR) ---
            int i = 0;
            for (; i + 2 <= cn; i += 2) {
                float ta0 = rdl_f(w0, i),     ta1 = rdl_f(w1, i),     ta2 = rdl_f(w2, i);
                int   sa  = __builtin_amdgcn_readlane(srcv, i);
                float tb0 = rdl_f(w0, i + 1), tb1 = rdl_f(w1, i + 1), tb2 = rdl_f(w2, i + 1);
                int   sb  = __builtin_amdgcn_readlane(srcv, i + 1);
                unsigned ia = (unsigned)sa * 96u + lane;
                unsigned ib = (unsigned)sb * 96u + lane;
                unsigned va = xs32[ia];
                unsigned vb = xs32[ib];
                float xa2 = bf2f(xsb[(ia << 1) + c128ml]);
                float xb2 = bf2f(xsb[(ib << 1) + c128ml]);
                a0A += ta0 * bf_lo(va); a1A += ta1 * bf_hi(va); a2A += ta2 * xa2;
                a0B += tb0 * bf_lo(vb); a1B += tb1 * bf_hi(vb); a2B += tb2 * xb2;
            }
            if (i < cn) {
                float ta0 = rdl_f(w0, i), ta1 = rdl_f(w1, i), ta2 = rdl_f(w2, i);
                int   sa  = __builtin_amdgcn_readlane(srcv, i);
                unsigned ia = (unsigned)sa * 96u + lane;
                unsigned va = xs32[ia];
                a0A += ta0 * bf_lo(va);
                a1A += ta1 * bf_hi(va);
                a2A += ta2 * bf2f(xsb[(ia << 1) + c128ml]);
            }
        }

        // reduce per-lane partials (den, ae)
        #pragma unroll
        for (int o = 32; o; o >>= 1) {
            pden0 += __shfl_xor(pden0, o, 64);
            pden1 += __shfl_xor(pden1, o, 64);
            pden2 += __shfl_xor(pden2, o, 64);
            pae0  += __shfl_xor(pae0, o, 64);
            pae1  += __shfl_xor(pae1, o, 64);
            pae2  += __shfl_xor(pae2, o, 64);
        }

        // self loop (edge attr = mean of incoming, 0 if deg==0); all pre-scaled
        float dc = fmaxf((float)deg, 1.0f);
        float inv_dc = __builtin_amdgcn_rcpf(dc);
        float sl0 = leaky(a_src[n * HH + 0] + a_dst[n * HH + 0] + pae0 * inv_dc);
        float sl1 = leaky(a_src[n * HH + 1] + a_dst[n * HH + 1] + pae1 * inv_dc);
        float sl2 = leaky(a_src[n * HH + 2] + a_dst[n * HH + 2] + pae2 * inv_dc);
        float e0 = exp2f(sl0), e1 = exp2f(sl1), e2 = exp2f(sl2);
        unsigned ian = (unsigned)n * 96u + lane;
        unsigned van = xs32[ian];
        float xn2 = bf2f(xsb[(ian << 1) + c128ml]);
        float r0 = __builtin_amdgcn_rcpf(pden0 + e0);
        float r1 = __builtin_amdgcn_rcpf(pden1 + e1);
        float r2 = __builtin_amdgcn_rcpf(pden2 + e2);
        float acc0 = (a0A + a0B + e0 * bf_lo(van)) * r0;
        float acc1 = (a1A + a1B + e1 * bf_hi(van)) * r1;
        float acc2 = (a2A + a2B + e2 * xn2) * r2;
        size_t nbse = (size_t)n * HC;
        oaccb[nbse + 0 * CC + lane] = f2bf(acc0);
        oaccb[nbse + 1 * CC + lane] = f2bf(acc1);
        oaccb[nbse + 2 * CC + lane] = f2bf(acc2);
    }
}

// ---------- fused MLP: GEMM1 -> LN1 -> GEMM2 -> LN2 (MFMA, in-reg LN) ----------
__global__ __launch_bounds__(256) void k_mlp(const unsigned short* __restrict__ oaccb,
                                             const unsigned short* __restrict__ w1t,
                                             const unsigned short* __restrict__ w2t,
                                             const float* __restrict__ b1p,
                                             const float* __restrict__ x,
                                             const float* __restrict__ g1,
                                             const float* __restrict__ be1,
                                             const float* __restrict__ b2,
                                             const float* __restrict__ g2,
                                             const float* __restrict__ be2,
                                             float* __restrict__ out, int N) {
    __shared__ unsigned short H1[64 * 72];   // [node-in-tile][feature] bf16, pad 72
    int lane = threadIdx.x & 63, w = threadIdx.x >> 6;
    int l15 = lane & 15, kg = (lane >> 4) * 8;
    int nb = blockIdx.x * 64;
    int arow = nb + w * 16 + l15;
    int arow_c = min(arow, N - 1);

    float c_b1[4], c_g1[4], c_be1[4], c_b2[4], c_g2[4], c_be2[4];
    #pragma unroll
    for (int ct = 0; ct < 4; ++ct) {
        int c = ct * 16 + l15;
        c_b1[ct] = b1p[c]; c_g1[ct] = g1[c]; c_be1[ct] = be1[c];
        c_b2[ct] = b2[c];  c_g2[ct] = g2[c]; c_be2[ct] = be2[c];
    }

    // GEMM1: [64 x 192] @ [192 x 64], A read directly as bf16
    f32x4 acc[4];
    #pragma unroll
    for (int ct = 0; ct < 4; ++ct) acc[ct] = (f32x4){0.f, 0.f, 0.f, 0.f};
    #pragma unroll
    for (int k0 = 0; k0 < HC; k0 += 32) {
        bf16x8 af = *(const bf16x8*)(oaccb + (size_t)arow_c * HC + k0 + kg);
        #pragma unroll
        for (int ct = 0; ct < 4; ++ct) {
            bf16x8 bf = *(const bf16x8*)(w1t + (size_t)(ct * 16 + l15) * HC + k0 + kg);
            acc[ct] = __builtin_amdgcn_mfma_f32_16x16x32_bf16(af, bf, acc[ct], 0, 0, 0);
        }
    }

    // epilogue1: y = acc + b1' + x ; LN1 -> h1 (regs + LDS bf16)
    int rbase = nb + w * 16 + (lane >> 4) * 4;
    int rloc0 = w * 16 + (lane >> 4) * 4;
    float h1v[4][4];
    float y[4][4];
    #pragma unroll
    for (int j = 0; j < 4; ++j) {
        int r = min(rbase + j, N - 1);
        #pragma unroll
        for (int ct = 0; ct < 4; ++ct)
            y[ct][j] = acc[ct][j] + c_b1[ct] + x[(size_t)r * DIN + ct * 16 + l15];
    }
    #pragma unroll
    for (int j = 0; j < 4; ++j) {
        float s = y[0][j] + y[1][j] + y[2][j] + y[3][j];
        #pragma unroll
        for (int o = 1; o < 16; o <<= 1) s += __shfl_xor(s, o, 64);
        float m = s * (1.0f / CC);
        float vs = 0.f;
        #pragma unroll
        for (int ct = 0; ct < 4; ++ct) { float d = y[ct][j] - m; vs += d * d; }
        #pragma unroll
        for (int o = 1; o < 16; o <<= 1) vs += __shfl_xor(vs, o, 64);
        float inv = rsqrtf(vs * (1.0f / CC) + LN_EPS);
        #pragma unroll
        for (int ct = 0; ct < 4; ++ct) {
            float h = (y[ct][j] - m) * inv * c_g1[ct] + c_be1[ct];
            h1v[ct][j] = h;
            H1[(rloc0 + j) * 72 + ct * 16 + l15] = f2bf(h);
        }
    }
    __syncthreads();

    // GEMM2: [64 x 64] @ [64 x 64]
    f32x4 acc2[4];
    #pragma unroll
    for (int ct = 0; ct < 4; ++ct) acc2[ct] = (f32x4){0.f, 0.f, 0.f, 0.f};
    #pragma unroll
    for (int k0 = 0; k0 < CC; k0 += 32) {
        bf16x8 af = *(const bf16x8*)&H1[(w * 16 + l15) * 72 + k0 + kg];
        #pragma unroll
        for (int ct = 0; ct < 4; ++ct) {
            bf16x8 bf = *(const bf16x8*)(w2t + (size_t)(ct * 16 + l15) * CC + k0 + kg);
            acc2[ct] = __builtin_amdgcn_mfma_f32_16x16x32_bf16(af, bf, acc2[ct], 0, 0, 0);
        }
    }

    // epilogue2: z = acc2 + b2 + h1 ; LN2 -> out
    #pragma unroll
    for (int j = 0; j < 4; ++j) {
        float z0 = acc2[0][j] + c_b2[0] + h1v[0][j];
        float z1 = acc2[1][j] + c_b2[1] + h1v[1][j];
        float z2 = acc2[2][j] + c_b2[2] + h1v[2][j];
        float z3 = acc2[3][j] + c_b2[3] + h1v[3][j];
        float s = z0 + z1 + z2 + z3;
        #pragma unroll
        for (int o = 1; o < 16; o <<= 1) s += __shfl_xor(s, o, 64);
        float m = s * (1.0f / CC);
        float d0 = z0 - m, d1 = z1 - m, d2 = z2 - m, d3 = z3 - m;
        float vs = d0 * d0 + d1 * d1 + d2 * d2 + d3 * d3;
        #pragma unroll
        for (int o = 1; o < 16; o <<= 1) vs += __shfl_xor(vs, o, 64);
        float inv = rsqrtf(vs * (1.0f / CC) + LN_EPS);
        int r = rbase + j;
        if (r < N) {
            out[(size_t)r * CC + 0 * 16 + l15] = d0 * inv * c_g2[0] + c_be2[0];
            out[(size_t)r * CC + 1 * 16 + l15] = d1 * inv * c_g2[1] + c_be2[1];
            out[(size_t)r * CC + 2 * 16 + l15] = d2 * inv * c_g2[2] + c_be2[2];
            out[(size_t)r * CC + 3 * 16 + l15] = d3 * inv * c_g2[3] + c_be2[3];
        }
    }
}

extern "C" void kernel_launch(void* const* d_in, const int* in_sizes, int n_in,
                              void* d_out, int out_size, void* d_ws, size_t ws_size,
                              hipStream_t stream) {
    const float* x          = (const float*)d_in[0];
    const float* edge_attr  = (const float*)d_in[1];
    const float* lin_w      = (const float*)d_in[2];
    const float* att_src    = (const float*)d_in[3];
    const float* att_dst    = (const float*)d_in[4];
    const float* lin_edge_w = (const float*)d_in[5];
    const float* att_edge   = (const float*)d_in[6];
    const float* gat_bias   = (const float*)d_in[7];
    const float* w1         = (const float*)d_in[8];
    const float* b1         = (const float*)d_in[9];
    const float* ln1_g      = (const float*)d_in[10];
    const float* ln1_b      = (const float*)d_in[11];
    const float* w2         = (const float*)d_in[12];
    const float* b2         = (const float*)d_in[13];
    const float* ln2_g      = (const float*)d_in[14];
    const float* ln2_b      = (const float*)d_in[15];
    const int*   ei         = (const int*)d_in[16];
    float* out = (float*)d_out;

    const int N = in_sizes[0] / DIN;
    const int E = in_sizes[1] / ED;
    const int nb_scan = (N + 255) / 256;

    char* ws = (char*)d_ws;
    size_t off_b = 0;
    auto alloc = [&](size_t bytes) {
        size_t o = off_b;
        off_b = (off_b + bytes + 255) & ~(size_t)255;
        return o;
    };
    // zeroed region first (single memset)
    int* icnt = (int*)(ws + alloc((size_t)N * 4));
    int* gtot = (int*)(ws + alloc(4));
    size_t zero_bytes = off_b;
    // fully-overwritten region
    unsigned short* xsb   = (unsigned short*)(ws + alloc((size_t)N * HC * 2));
    unsigned short* oaccb = (unsigned short*)(ws + alloc((size_t)N * HC * 2));
    float*  a_srcb  = (float*)(ws + alloc((size_t)N * HH * 4));
    float*  a_dstb  = (float*)(ws + alloc((size_t)N * HH * 4));
    int*    offb    = (int*)(ws + alloc((size_t)N * 4));
    int*    cursor  = (int*)(ws + alloc((size_t)N * 4));
    uint4*  payload = (uint4*)(ws + alloc((size_t)E * 16));
    unsigned short* linwt = (unsigned short*)(ws + alloc((size_t)HC * DIN * 2));
    unsigned short* w1t   = (unsigned short*)(ws + alloc((size_t)DIN * HC * 2));
    unsigned short* w2t   = (unsigned short*)(ws + alloc((size_t)CC * CC * 2));
    float* b1p = (float*)(ws + alloc((size_t)CC * 4));
    float* we  = (float*)(ws + alloc((size_t)ED * HH * 4));
    (void)ws_size; (void)n_in; (void)out_size;

    hipMemsetAsync(d_ws, 0, zero_bytes, stream);

    k_prep_cnt<<<PREP_BLOCKS + (E + 255) / 256, 256, 0, stream>>>(
        lin_w, w1, w2, b1, gat_bias, lin_edge_w, att_edge,
        linwt, w1t, w2t, b1p, we, ei, icnt, E);
    k_xs<<<(N + 63) / 64, 256, 0, stream>>>(x, linwt, att_src, att_dst, xsb, a_srcb, a_dstb, N);
    k_scanA<<<nb_scan, 256, 0, stream>>>(icnt, gtot, offb, cursor, N);
    k_fill<<<(E + 255) / 256, 256, 0, stream>>>(edge_attr, ei, a_srcb, a_dstb, we, cursor,
                                                payload, E);
    k_gat<<<(N + 3) / 4, 256, 0, stream>>>(xsb, a_srcb, a_dstb, offb, icnt, payload, oaccb, N);
    k_mlp<<<(N + 63) / 64, 256, 0, stream>>>(oaccb, w1t, w2t, b1p, x,
                                             ln1_g, ln1_b, b2, ln2_g, ln2_b, out, N);
}

// Round 12
// 184.911 us; speedup vs baseline: 1.1070x; 1.0105x over previous
//
#include <hip/hip_runtime.h>

// GraphTransformerBlock2: GATConv(H=3,C=64, edge_dim=5, self-loops w/ mean fill)
// -> linear1 -> LN(x + .) -> linear2 -> LN(lin + .)
// All float32 I/O. edge_index int32 (2,E): src=ei[0:E], dst=ei[E:2E].
//
// R11 (consolidation):
//  - k_gat phase B back to R9's wbuf LDS broadcast (readlane moved the
//    broadcast onto the busy VALU pipe: 58->72% VALUBusy, 52.6->54.0us).
//  - scan fused into k_xs as extra blocks (one fewer dispatch).
//  - k_fill: cursor atomic issued before logit math (latency hiding).

#define HH 3
#define CC 64
#define DIN 64
#define ED 5
#define HC 192
#define NEG_SLOPE 0.2f
#define LN_EPS 1e-5f
#define LOG2E 1.44269504f

typedef __attribute__((ext_vector_type(8))) short bf16x8;
typedef __attribute__((ext_vector_type(4))) float f32x4;

__device__ __forceinline__ float leaky(float l) { return fmaxf(l, NEG_SLOPE * l); }

__device__ __forceinline__ unsigned short f2bf(float f) {
    unsigned u = __float_as_uint(f);
    unsigned r = (u + 0x7FFFu + ((u >> 16) & 1u)) >> 16;   // RNE
    return (unsigned short)r;
}
__device__ __forceinline__ float bf2f(unsigned short u) {
    return __uint_as_float((unsigned)u << 16);
}
__device__ __forceinline__ float bf_lo(unsigned v) { return __uint_as_float(v << 16); }
__device__ __forceinline__ float bf_hi(unsigned v) { return __uint_as_float(v & 0xFFFF0000u); }

__device__ __forceinline__ bf16x8 pack8(float4 a, float4 b) {
    bf16x8 r;
    r[0] = (short)f2bf(a.x); r[1] = (short)f2bf(a.y);
    r[2] = (short)f2bf(a.z); r[3] = (short)f2bf(a.w);
    r[4] = (short)f2bf(b.x); r[5] = (short)f2bf(b.y);
    r[6] = (short)f2bf(b.z); r[7] = (short)f2bf(b.w);
    return r;
}

// ---------- prep (bf16 transposed weights + folded bias + we*log2e) + cnt ----------
#define PREP_TOT (HC*DIN + DIN*HC + CC*CC + CC + ED*HH)
#define PREP_BLOCKS 30
__global__ __launch_bounds__(256) void k_prep_cnt(const float* __restrict__ lin_w,
                                                  const float* __restrict__ w1,
                                                  const float* __restrict__ w2,
                                                  const float* __restrict__ b1,
                                                  const float* __restrict__ gat_bias,
                                                  const float* __restrict__ lin_edge_w,
                                                  const float* __restrict__ att_edge,
                                                  unsigned short* __restrict__ linwt,
                                                  unsigned short* __restrict__ w1t,
                                                  unsigned short* __restrict__ w2t,
                                                  float* __restrict__ b1p,
                                                  float* __restrict__ we,
                                                  const int* __restrict__ ei,
                                                  int* __restrict__ icnt, int E) {
    if (blockIdx.x < PREP_BLOCKS) {
        for (int i = blockIdx.x * 256 + threadIdx.x; i < PREP_TOT; i += PREP_BLOCKS * 256) {
            if (i < HC * DIN) {
                int c = i >> 6, k = i & 63;
                linwt[i] = f2bf(lin_w[k * HC + c]);
            } else if (i < 2 * HC * DIN) {
                int j = i - HC * DIN;
                int c = j / HC, k = j - c * HC;
                w1t[j] = f2bf(w1[k * CC + c]);
            } else if (i < 2 * HC * DIN + CC * CC) {
                int j = i - 2 * HC * DIN;
                int c = j >> 6, k = j & 63;
                w2t[j] = f2bf(w2[k * CC + c]);
            } else if (i < 2 * HC * DIN + CC * CC + CC) {
                int c = i - (2 * HC * DIN + CC * CC);
                float s = b1[c];
                for (int k = 0; k < HC; ++k) s += gat_bias[k] * w1[k * CC + c];
                b1p[c] = s;
            } else {
                int q = i - (2 * HC * DIN + CC * CC + CC);
                int d = q / HH, h = q - d * HH;
                float s = 0.f;
                for (int c = 0; c < CC; ++c)
                    s += lin_edge_w[d * HC + h * CC + c] * att_edge[h * CC + c];
                we[q] = s * LOG2E;                     // pre-scale for exp2
            }
        }
    } else {
        int nb = gridDim.x - PREP_BLOCKS;
        for (int e = (blockIdx.x - PREP_BLOCKS) * 256 + threadIdx.x; e < E; e += nb * 256)
            atomicAdd(&icnt[ei[E + e]], 1);
    }
}

// ---------- xs = x @ lin_w (MFMA) -> packed xsb + a_src/a_dst;  scan fused ----------
// xsb row (stride HC u16): u32 word[c] = h0[c]|h1[c]<<16 for c<64; u16[128+c] = h2[c].
// Blocks >= nbx run the CSR allocation scan (block base via global atomic).
__global__ __launch_bounds__(256) void k_xs(const float* __restrict__ x,
                                            const unsigned short* __restrict__ linwt,
                                            const float* __restrict__ att_src,
                                            const float* __restrict__ att_dst,
                                            unsigned short* __restrict__ xsb,
                                            float* __restrict__ a_src,
                                            float* __restrict__ a_dst,
                                            const int* __restrict__ icnt,
                                            int* __restrict__ gtot,
                                            int* __restrict__ off,
                                            int* __restrict__ cursor,
                                            int N, int nbx) {
    __shared__ int wt[4];
    __shared__ int base_sh;
    if ((int)blockIdx.x >= nbx) {
        // ---- scan part (CSR allocation; off need not be monotone) ----
        int bid = blockIdx.x - nbx;
        int i = bid * 256 + threadIdx.x;
        int lane = threadIdx.x & 63, wid = threadIdx.x >> 6;
        int v = (i < N) ? icnt[i] : 0;
        int incl = v;
        #pragma unroll
        for (int o = 1; o < 64; o <<= 1) {
            int u = __shfl_up(incl, o, 64);
            if (lane >= o) incl += u;
        }
        if (lane == 63) wt[wid] = incl;
        __syncthreads();
        if (threadIdx.x == 0)
            base_sh = atomicAdd(gtot, wt[0] + wt[1] + wt[2] + wt[3]);
        __syncthreads();
        int wpre = 0;
        for (int w2 = 0; w2 < wid; ++w2) wpre += wt[w2];
        int excl = base_sh + wpre + incl - v;
        if (i < N) { off[i] = excl; cursor[i] = excl; }
        return;
    }

    int lane = threadIdx.x & 63, w = threadIdx.x >> 6;
    int l15 = lane & 15, kg = (lane >> 4) * 8;
    int nb = blockIdx.x * 64;
    int arow = nb + w * 16 + l15;
    int arow_c = min(arow, N - 1);

    f32x4 acc[12];
    #pragma unroll
    for (int ct = 0; ct < 12; ++ct) acc[ct] = (f32x4){0.f, 0.f, 0.f, 0.f};

    #pragma unroll
    for (int k0 = 0; k0 < DIN; k0 += 32) {
        const float* ap = x + (size_t)arow_c * DIN + k0 + kg;
        float4 a0 = *(const float4*)ap;
        float4 a1 = *(const float4*)(ap + 4);
        bf16x8 af = pack8(a0, a1);
        #pragma unroll
        for (int ct = 0; ct < 12; ++ct) {
            bf16x8 bf = *(const bf16x8*)(linwt + (size_t)(ct * 16 + l15) * DIN + k0 + kg);
            acc[ct] = __builtin_amdgcn_mfma_f32_16x16x32_bf16(af, bf, acc[ct], 0, 0, 0);
        }
    }

    float asv[12], adv[12];
    #pragma unroll
    for (int ct = 0; ct < 12; ++ct) {
        int c = ct * 16 + l15;
        asv[ct] = att_src[c]; adv[ct] = att_dst[c];
    }

    int rbase = nb + w * 16 + (lane >> 4) * 4;
    #pragma unroll
    for (int j = 0; j < 4; ++j) {
        int r = rbase + j;
        bool ok = r < N;
        float ps0 = 0.f, ps1 = 0.f, ps2 = 0.f, pd0 = 0.f, pd1 = 0.f, pd2 = 0.f;
        #pragma unroll
        for (int ct = 0; ct < 12; ++ct) {
            float v = acc[ct][j];
            float s = v * asv[ct], d = v * adv[ct];
            if (ct < 4)      { ps0 += s; pd0 += d; }
            else if (ct < 8) { ps1 += s; pd1 += d; }
            else             { ps2 += s; pd2 += d; }
        }
        if (ok) {
            unsigned* row32 = (unsigned*)(xsb + (size_t)r * HC);
            #pragma unroll
            for (int ct = 0; ct < 4; ++ct) {
                int c = ct * 16 + l15;
                row32[c] = (unsigned)f2bf(acc[ct][j]) | ((unsigned)f2bf(acc[ct + 4][j]) << 16);
                xsb[(size_t)r * HC + 128 + c] = f2bf(acc[ct + 8][j]);
            }
        }
        #pragma unroll
        for (int o = 1; o < 16; o <<= 1) {
            ps0 += __shfl_xor(ps0, o, 64); pd0 += __shfl_xor(pd0, o, 64);
            ps1 += __shfl_xor(ps1, o, 64); pd1 += __shfl_xor(pd1, o, 64);
            ps2 += __shfl_xor(ps2, o, 64); pd2 += __shfl_xor(pd2, o, 64);
        }
        if (ok && l15 == 0) {
            a_src[r * HH + 0] = ps0 * LOG2E; a_src[r * HH + 1] = ps1 * LOG2E;
            a_src[r * HH + 2] = ps2 * LOG2E;
            a_dst[r * HH + 0] = pd0 * LOG2E; a_dst[r * HH + 1] = pd1 * LOG2E;
            a_dst[r * HH + 2] = pd2 * LOG2E;
        }
    }
}

// ---------- payload fill (CSR order), 16B/edge, a_dst FOLDED IN ----------
// pk = { bf(lp0)|bf(lp1)<<16, bf(lp2)|bf(ae0)<<16, bf(ae1)|bf(ae2)<<16, src }
__global__ __launch_bounds__(256) void k_fill(const float* __restrict__ ea,
                                              const int* __restrict__ ei,
                                              const float* __restrict__ a_src,
                                              const float* __restrict__ a_dst,
                                              const float* __restrict__ we,
                                              int* __restrict__ cursor,
                                              uint4* __restrict__ payload, int E) {
    int e = blockIdx.x * blockDim.x + threadIdx.x;
    if (e >= E) return;
    int s = ei[e], d = ei[E + e];
    int pos = atomicAdd(&cursor[d], 1);                  // issue early; hide RMW latency
    float attr[ED];
    #pragma unroll
    for (int j = 0; j < ED; ++j) attr[j] = ea[(size_t)e * ED + j];
    float aeh[HH], lp[HH];
    #pragma unroll
    for (int h = 0; h < HH; ++h) {
        float a = 0.f;
        #pragma unroll
        for (int j = 0; j < ED; ++j) a += attr[j] * we[j * HH + h];   // we pre-scaled
        aeh[h] = a;
        lp[h] = a_src[s * HH + h] + a_dst[d * HH + h] + a;             // all pre-scaled
    }
    uint4 pk;
    pk.x = (unsigned)f2bf(lp[0])  | ((unsigned)f2bf(lp[1])  << 16);
    pk.y = (unsigned)f2bf(lp[2])  | ((unsigned)f2bf(aeh[0]) << 16);
    pk.z = (unsigned)f2bf(aeh[1]) | ((unsigned)f2bf(aeh[2]) << 16);
    pk.w = (unsigned)s;
    payload[pos] = pk;
}

// ---------- per-dst softmax + gather: two-phase, wbuf broadcast, 2-load gather ----------
__global__ __launch_bounds__(256) void k_gat(const unsigned short* __restrict__ xsb,
                                             const float* __restrict__ a_src,
                                             const float* __restrict__ a_dst,
                                             const int* __restrict__ off,
                                             const int* __restrict__ icnt,
                                             const uint4* __restrict__ payload,
                                             unsigned short* __restrict__ oaccb, int N) {
    __shared__ float4 wbuf[4][64];
    int lane = threadIdx.x & 63;
    int wid  = threadIdx.x >> 6;
    const unsigned* xs32 = (const unsigned*)xsb;
    unsigned c128ml = 128u - (unsigned)lane;            // (ia<<1)+c128ml = src*192+128+lane
    for (int n = blockIdx.x * 4 + wid; n < N; n += gridDim.x * 4) {
        int beg = off[n];
        int deg = icnt[n];

        float pden0 = 0.f, pden1 = 0.f, pden2 = 0.f;     // per-lane partials
        float pae0 = 0.f, pae1 = 0.f, pae2 = 0.f;
        float a0A = 0.f, a1A = 0.f, a2A = 0.f;
        float a0B = 0.f, a1B = 0.f, a2B = 0.f;

        for (int c0 = 0; c0 < deg; c0 += 64) {
            int cn = min(deg - c0, 64);
            // --- phase A: lane = edge (logits complete; just leaky+exp) ---
            float w0 = 0.f, w1 = 0.f, w2 = 0.f;
            int src = 0;
            if (lane < cn) {
                uint4 p = payload[beg + c0 + lane];
                w0 = exp2f(leaky(bf_lo(p.x)));
                w1 = exp2f(leaky(bf_hi(p.x)));
                w2 = exp2f(leaky(bf_lo(p.y)));
                pae0 += bf_hi(p.y);
                pae1 += bf_lo(p.z);
                pae2 += bf_hi(p.z);
                pden0 += w0; pden1 += w1; pden2 += w2;
                src = (int)p.w;
            }
            wbuf[wid][lane] = make_float4(w0, w1, w2, __int_as_float(src));
            // --- phase B: lane = feature, 2 loads per edge (u32 h0|h1, u16 h2) ---
            int i = 0;
            for (; i + 2 <= cn; i += 2) {
                float4 ta = wbuf[wid][i];
                float4 tb = wbuf[wid][i + 1];
                unsigned ia = __umul24((unsigned)__float_as_int(ta.w), 96u) + lane;
                unsigned ib = __umul24((unsigned)__float_as_int(tb.w), 96u) + lane;
                unsigned va = xs32[ia];
                unsigned vb = xs32[ib];
                float xa2 = bf2f(xsb[(ia << 1) + c128ml]);
                float xb2 = bf2f(xsb[(ib << 1) + c128ml]);
                a0A += ta.x * bf_lo(va); a1A += ta.y * bf_hi(va); a2A += ta.z * xa2;
                a0B += tb.x * bf_lo(vb); a1B += tb.y * bf_hi(vb); a2B += tb.z * xb2;
            }
            if (i < cn) {
                float4 ta = wbuf[wid][i];
                unsigned ia = __umul24((unsigned)__float_as_int(ta.w), 96u) + lane;
                unsigned va = xs32[ia];
                a0A += ta.x * bf_lo(va);
                a1A += ta.y * bf_hi(va);
                a2A += ta.z * bf2f(xsb[(ia << 1) + c128ml]);
            }
        }

        // reduce per-lane partials (den, ae)
        #pragma unroll
        for (int o = 32; o; o >>= 1) {
            pden0 += __shfl_xor(pden0, o, 64);
            pden1 += __shfl_xor(pden1, o, 64);
            pden2 += __shfl_xor(pden2, o, 64);
            pae0  += __shfl_xor(pae0, o, 64);
            pae1  += __shfl_xor(pae1, o, 64);
            pae2  += __shfl_xor(pae2, o, 64);
        }

        // self loop (edge attr = mean of incoming, 0 if deg==0); all pre-scaled
        float dc = fmaxf((float)deg, 1.0f);
        float inv_dc = __builtin_amdgcn_rcpf(dc);
        float sl0 = leaky(a_src[n * HH + 0] + a_dst[n * HH + 0] + pae0 * inv_dc);
        float sl1 = leaky(a_src[n * HH + 1] + a_dst[n * HH + 1] + pae1 * inv_dc);
        float sl2 = leaky(a_src[n * HH + 2] + a_dst[n * HH + 2] + pae2 * inv_dc);
        float e0 = exp2f(sl0), e1 = exp2f(sl1), e2 = exp2f(sl2);
        unsigned ian = __umul24((unsigned)n, 96u) + lane;
        unsigned van = xs32[ian];
        float xn2 = bf2f(xsb[(ian << 1) + c128ml]);
        float r0 = __builtin_amdgcn_rcpf(pden0 + e0);
        float r1 = __builtin_amdgcn_rcpf(pden1 + e1);
        float r2 = __builtin_amdgcn_rcpf(pden2 + e2);
        float acc0 = (a0A + a0B + e0 * bf_lo(van)) * r0;
        float acc1 = (a1A + a1B + e1 * bf_hi(van)) * r1;
        float acc2 = (a2A + a2B + e2 * xn2) * r2;
        size_t nbse = (size_t)n * HC;
        oaccb[nbse + 0 * CC + lane] = f2bf(acc0);
        oaccb[nbse + 1 * CC + lane] = f2bf(acc1);
        oaccb[nbse + 2 * CC + lane] = f2bf(acc2);
    }
}

// ---------- fused MLP: GEMM1 -> LN1 -> GEMM2 -> LN2 (MFMA, in-reg LN) ----------
__global__ __launch_bounds__(256) void k_mlp(const unsigned short* __restrict__ oaccb,
                                             const unsigned short* __restrict__ w1t,
                                             const unsigned short* __restrict__ w2t,
                                             const float* __restrict__ b1p,
                                             const float* __restrict__ x,
                                             const float* __restrict__ g1,
                                             const float* __restrict__ be1,
                                             const float* __restrict__ b2,
                                             const float* __restrict__ g2,
                                             const float* __restrict__ be2,
                                             float* __restrict__ out, int N) {
    __shared__ unsigned short H1[64 * 72];   // [node-in-tile][feature] bf16, pad 72
    int lane = threadIdx.x & 63, w = threadIdx.x >> 6;
    int l15 = lane & 15, kg = (lane >> 4) * 8;
    int nb = blockIdx.x * 64;
    int arow = nb + w * 16 + l15;
    int arow_c = min(arow, N - 1);

    float c_b1[4], c_g1[4], c_be1[4], c_b2[4], c_g2[4], c_be2[4];
    #pragma unroll
    for (int ct = 0; ct < 4; ++ct) {
        int c = ct * 16 + l15;
        c_b1[ct] = b1p[c]; c_g1[ct] = g1[c]; c_be1[ct] = be1[c];
        c_b2[ct] = b2[c];  c_g2[ct] = g2[c]; c_be2[ct] = be2[c];
    }

    // GEMM1: [64 x 192] @ [192 x 64], A read directly as bf16
    f32x4 acc[4];
    #pragma unroll
    for (int ct = 0; ct < 4; ++ct) acc[ct] = (f32x4){0.f, 0.f, 0.f, 0.f};
    #pragma unroll
    for (int k0 = 0; k0 < HC; k0 += 32) {
        bf16x8 af = *(const bf16x8*)(oaccb + (size_t)arow_c * HC + k0 + kg);
        #pragma unroll
        for (int ct = 0; ct < 4; ++ct) {
            bf16x8 bf = *(const bf16x8*)(w1t + (size_t)(ct * 16 + l15) * HC + k0 + kg);
            acc[ct] = __builtin_amdgcn_mfma_f32_16x16x32_bf16(af, bf, acc[ct], 0, 0, 0);
        }
    }

    // epilogue1: y = acc + b1' + x ; LN1 -> h1 (regs + LDS bf16)
    int rbase = nb + w * 16 + (lane >> 4) * 4;
    int rloc0 = w * 16 + (lane >> 4) * 4;
    float h1v[4][4];
    float y[4][4];
    #pragma unroll
    for (int j = 0; j < 4; ++j) {
        int r = min(rbase + j, N - 1);
        #pragma unroll
        for (int ct = 0; ct < 4; ++ct)
            y[ct][j] = acc[ct][j] + c_b1[ct] + x[(size_t)r * DIN + ct * 16 + l15];
    }
    #pragma unroll
    for (int j = 0; j < 4; ++j) {
        float s = y[0][j] + y[1][j] + y[2][j] + y[3][j];
        #pragma unroll
        for (int o = 1; o < 16; o <<= 1) s += __shfl_xor(s, o, 64);
        float m = s * (1.0f / CC);
        float vs = 0.f;
        #pragma unroll
        for (int ct = 0; ct < 4; ++ct) { float d = y[ct][j] - m; vs += d * d; }
        #pragma unroll
        for (int o = 1; o < 16; o <<= 1) vs += __shfl_xor(vs, o, 64);
        float inv = rsqrtf(vs * (1.0f / CC) + LN_EPS);
        #pragma unroll
        for (int ct = 0; ct < 4; ++ct) {
            float h = (y[ct][j] - m) * inv * c_g1[ct] + c_be1[ct];
            h1v[ct][j] = h;
            H1[(rloc0 + j) * 72 + ct * 16 + l15] = f2bf(h);
        }
    }
    __syncthreads();

    // GEMM2: [64 x 64] @ [64 x 64]
    f32x4 acc2[4];
    #pragma unroll
    for (int ct = 0; ct < 4; ++ct) acc2[ct] = (f32x4){0.f, 0.f, 0.f, 0.f};
    #pragma unroll
    for (int k0 = 0; k0 < CC; k0 += 32) {
        bf16x8 af = *(const bf16x8*)&H1[(w * 16 + l15) * 72 + k0 + kg];
        #pragma unroll
        for (int ct = 0; ct < 4; ++ct) {
            bf16x8 bf = *(const bf16x8*)(w2t + (size_t)(ct * 16 + l15) * CC + k0 + kg);
            acc2[ct] = __builtin_amdgcn_mfma_f32_16x16x32_bf16(af, bf, acc2[ct], 0, 0, 0);
        }
    }

    // epilogue2: z = acc2 + b2 + h1 ; LN2 -> out
    #pragma unroll
    for (int j = 0; j < 4; ++j) {
        float z0 = acc2[0][j] + c_b2[0] + h1v[0][j];
        float z1 = acc2[1][j] + c_b2[1] + h1v[1][j];
        float z2 = acc2[2][j] + c_b2[2] + h1v[2][j];
        float z3 = acc2[3][j] + c_b2[3] + h1v[3][j];
        float s = z0 + z1 + z2 + z3;
        #pragma unroll
        for (int o = 1; o < 16; o <<= 1) s += __shfl_xor(s, o, 64);
        float m = s * (1.0f / CC);
        float d0 = z0 - m, d1 = z1 - m, d2 = z2 - m, d3 = z3 - m;
        float vs = d0 * d0 + d1 * d1 + d2 * d2 + d3 * d3;
        #pragma unroll
        for (int o = 1; o < 16; o <<= 1) vs += __shfl_xor(vs, o, 64);
        float inv = rsqrtf(vs * (1.0f / CC) + LN_EPS);
        int r = rbase + j;
        if (r < N) {
            out[(size_t)r * CC + 0 * 16 + l15] = d0 * inv * c_g2[0] + c_be2[0];
            out[(size_t)r * CC + 1 * 16 + l15] = d1 * inv * c_g2[1] + c_be2[1];
            out[(size_t)r * CC + 2 * 16 + l15] = d2 * inv * c_g2[2] + c_be2[2];
            out[(size_t)r * CC + 3 * 16 + l15] = d3 * inv * c_g2[3] + c_be2[3];
        }
    }
}

extern "C" void kernel_launch(void* const* d_in, const int* in_sizes, int n_in,
                              void* d_out, int out_size, void* d_ws, size_t ws_size,
                              hipStream_t stream) {
    const float* x          = (const float*)d_in[0];
    const float* edge_attr  = (const float*)d_in[1];
    const float* lin_w      = (const float*)d_in[2];
    const float* att_src    = (const float*)d_in[3];
    const float* att_dst    = (const float*)d_in[4];
    const float* lin_edge_w = (const float*)d_in[5];
    const float* att_edge   = (const float*)d_in[6];
    const float* gat_bias   = (const float*)d_in[7];
    const float* w1         = (const float*)d_in[8];
    const float* b1         = (const float*)d_in[9];
    const float* ln1_g      = (const float*)d_in[10];
    const float* ln1_b      = (const float*)d_in[11];
    const float* w2         = (const float*)d_in[12];
    const float* b2         = (const float*)d_in[13];
    const float* ln2_g      = (const float*)d_in[14];
    const float* ln2_b      = (const float*)d_in[15];
    const int*   ei         = (const int*)d_in[16];
    float* out = (float*)d_out;

    const int N = in_sizes[0] / DIN;
    const int E = in_sizes[1] / ED;
    const int nb_scan = (N + 255) / 256;
    const int nbx = (N + 63) / 64;

    char* ws = (char*)d_ws;
    size_t off_b = 0;
    auto alloc = [&](size_t bytes) {
        size_t o = off_b;
        off_b = (off_b + bytes + 255) & ~(size_t)255;
        return o;
    };
    // zeroed region first (single memset)
    int* icnt = (int*)(ws + alloc((size_t)N * 4));
    int* gtot = (int*)(ws + alloc(4));
    size_t zero_bytes = off_b;
    // fully-overwritten region
    unsigned short* xsb   = (unsigned short*)(ws + alloc((size_t)N * HC * 2));
    unsigned short* oaccb = (unsigned short*)(ws + alloc((size_t)N * HC * 2));
    float*  a_srcb  = (float*)(ws + alloc((size_t)N * HH * 4));
    float*  a_dstb  = (float*)(ws + alloc((size_t)N * HH * 4));
    int*    offb    = (int*)(ws + alloc((size_t)N * 4));
    int*    cursor  = (int*)(ws + alloc((size_t)N * 4));
    uint4*  payload = (uint4*)(ws + alloc((size_t)E * 16));
    unsigned short* linwt = (unsigned short*)(ws + alloc((size_t)HC * DIN * 2));
    unsigned short* w1t   = (unsigned short*)(ws + alloc((size_t)DIN * HC * 2));
    unsigned short* w2t   = (unsigned short*)(ws + alloc((size_t)CC * CC * 2));
    float* b1p = (float*)(ws + alloc((size_t)CC * 4));
    float* we  = (float*)(ws + alloc((size_t)ED * HH * 4));
    (void)ws_size; (void)n_in; (void)out_size;

    hipMemsetAsync(d_ws, 0, zero_bytes, stream);

    k_prep_cnt<<<PREP_BLOCKS + (E + 255) / 256, 256, 0, stream>>>(
        lin_w, w1, w2, b1, gat_bias, lin_edge_w, att_edge,
        linwt, w1t, w2t, b1p, we, ei, icnt, E);
    k_xs<<<nbx + nb_scan, 256, 0, stream>>>(x, linwt, att_src, att_dst, xsb,
                                            a_srcb, a_dstb, icnt, gtot, offb, cursor,
                                            N, nbx);
    k_fill<<<(E + 255) / 256, 256, 0, stream>>>(edge_attr, ei, a_srcb, a_dstb, we, cursor,
                                                payload, E);
    k_gat<<<(N + 3) / 4, 256, 0, stream>>>(xsb, a_srcb, a_dstb, offb, icnt, payload, oaccb, N);
    k_mlp<<<(N + 63) / 64, 256, 0, stream>>>(oaccb, w1t, w2t, b1p, x,
                                             ln1_g, ln1_b, b2, ln2_g, ln2_b, out, N);
}

// Round 13
// 184.135 us; speedup vs baseline: 1.1117x; 1.0042x over previous
//
#include <hip/hip_runtime.h>

// GraphTransformerBlock2: GATConv(H=3,C=64, edge_dim=5, self-loops w/ mean fill)
// -> linear1 -> LN(x + .) -> linear2 -> LN(lin + .)
// All float32 I/O. edge_index int32 (2,E): src=ei[0:E], dst=ei[E:2E].
//
// R12: k_mlp FUSED into k_gat as a 16-node-tile epilogue (k_gatmlp).
//  - block = 4 waves = 16 nodes; gather keeps 1-node-per-wave pattern
//    (4 serial nodes/wave) -> occupancy preserved (12500 waves total).
//  - oacc goes to a 6KB LDS tile instead of global (kills 38.4MB round-trip).
//  - MLP: wave w owns cols w*16..w*16+15; GEMM1 6 MFMA + GEMM2 2 MFMA per
//    wave; LN row-sums cross waves via 512B LDS partials (E[x^2]-m^2).
//  - one fewer dispatch (5 total incl. memset).

#define HH 3
#define CC 64
#define DIN 64
#define ED 5
#define HC 192
#define NEG_SLOPE 0.2f
#define LN_EPS 1e-5f
#define LOG2E 1.44269504f

typedef __attribute__((ext_vector_type(8))) short bf16x8;
typedef __attribute__((ext_vector_type(4))) float f32x4;

__device__ __forceinline__ float leaky(float l) { return fmaxf(l, NEG_SLOPE * l); }

__device__ __forceinline__ unsigned short f2bf(float f) {
    unsigned u = __float_as_uint(f);
    unsigned r = (u + 0x7FFFu + ((u >> 16) & 1u)) >> 16;   // RNE
    return (unsigned short)r;
}
__device__ __forceinline__ float bf2f(unsigned short u) {
    return __uint_as_float((unsigned)u << 16);
}
__device__ __forceinline__ float bf_lo(unsigned v) { return __uint_as_float(v << 16); }
__device__ __forceinline__ float bf_hi(unsigned v) { return __uint_as_float(v & 0xFFFF0000u); }

__device__ __forceinline__ bf16x8 pack8(float4 a, float4 b) {
    bf16x8 r;
    r[0] = (short)f2bf(a.x); r[1] = (short)f2bf(a.y);
    r[2] = (short)f2bf(a.z); r[3] = (short)f2bf(a.w);
    r[4] = (short)f2bf(b.x); r[5] = (short)f2bf(b.y);
    r[6] = (short)f2bf(b.z); r[7] = (short)f2bf(b.w);
    return r;
}

// ---------- prep (bf16 transposed weights + folded bias + we*log2e) + cnt ----------
#define PREP_TOT (HC*DIN + DIN*HC + CC*CC + CC + ED*HH)
#define PREP_BLOCKS 30
__global__ __launch_bounds__(256) void k_prep_cnt(const float* __restrict__ lin_w,
                                                  const float* __restrict__ w1,
                                                  const float* __restrict__ w2,
                                                  const float* __restrict__ b1,
                                                  const float* __restrict__ gat_bias,
                                                  const float* __restrict__ lin_edge_w,
                                                  const float* __restrict__ att_edge,
                                                  unsigned short* __restrict__ linwt,
                                                  unsigned short* __restrict__ w1t,
                                                  unsigned short* __restrict__ w2t,
                                                  float* __restrict__ b1p,
                                                  float* __restrict__ we,
                                                  const int* __restrict__ ei,
                                                  int* __restrict__ icnt, int E) {
    if (blockIdx.x < PREP_BLOCKS) {
        for (int i = blockIdx.x * 256 + threadIdx.x; i < PREP_TOT; i += PREP_BLOCKS * 256) {
            if (i < HC * DIN) {
                int c = i >> 6, k = i & 63;
                linwt[i] = f2bf(lin_w[k * HC + c]);
            } else if (i < 2 * HC * DIN) {
                int j = i - HC * DIN;
                int c = j / HC, k = j - c * HC;
                w1t[j] = f2bf(w1[k * CC + c]);
            } else if (i < 2 * HC * DIN + CC * CC) {
                int j = i - 2 * HC * DIN;
                int c = j >> 6, k = j & 63;
                w2t[j] = f2bf(w2[k * CC + c]);
            } else if (i < 2 * HC * DIN + CC * CC + CC) {
                int c = i - (2 * HC * DIN + CC * CC);
                float s = b1[c];
                for (int k = 0; k < HC; ++k) s += gat_bias[k] * w1[k * CC + c];
                b1p[c] = s;
            } else {
                int q = i - (2 * HC * DIN + CC * CC + CC);
                int d = q / HH, h = q - d * HH;
                float s = 0.f;
                for (int c = 0; c < CC; ++c)
                    s += lin_edge_w[d * HC + h * CC + c] * att_edge[h * CC + c];
                we[q] = s * LOG2E;                     // pre-scale for exp2
            }
        }
    } else {
        int nb = gridDim.x - PREP_BLOCKS;
        for (int e = (blockIdx.x - PREP_BLOCKS) * 256 + threadIdx.x; e < E; e += nb * 256)
            atomicAdd(&icnt[ei[E + e]], 1);
    }
}

// ---------- xs = x @ lin_w (MFMA) -> packed xsb + a_src/a_dst;  scan fused ----------
__global__ __launch_bounds__(256) void k_xs(const float* __restrict__ x,
                                            const unsigned short* __restrict__ linwt,
                                            const float* __restrict__ att_src,
                                            const float* __restrict__ att_dst,
                                            unsigned short* __restrict__ xsb,
                                            float* __restrict__ a_src,
                                            float* __restrict__ a_dst,
                                            const int* __restrict__ icnt,
                                            int* __restrict__ gtot,
                                            int* __restrict__ off,
                                            int* __restrict__ cursor,
                                            int N, int nbx) {
    __shared__ int wt[4];
    __shared__ int base_sh;
    if ((int)blockIdx.x >= nbx) {
        // ---- scan part (CSR allocation; off need not be monotone) ----
        int bid = blockIdx.x - nbx;
        int i = bid * 256 + threadIdx.x;
        int lane = threadIdx.x & 63, wid = threadIdx.x >> 6;
        int v = (i < N) ? icnt[i] : 0;
        int incl = v;
        #pragma unroll
        for (int o = 1; o < 64; o <<= 1) {
            int u = __shfl_up(incl, o, 64);
            if (lane >= o) incl += u;
        }
        if (lane == 63) wt[wid] = incl;
        __syncthreads();
        if (threadIdx.x == 0)
            base_sh = atomicAdd(gtot, wt[0] + wt[1] + wt[2] + wt[3]);
        __syncthreads();
        int wpre = 0;
        for (int w2 = 0; w2 < wid; ++w2) wpre += wt[w2];
        int excl = base_sh + wpre + incl - v;
        if (i < N) { off[i] = excl; cursor[i] = excl; }
        return;
    }

    int lane = threadIdx.x & 63, w = threadIdx.x >> 6;
    int l15 = lane & 15, kg = (lane >> 4) * 8;
    int nb = blockIdx.x * 64;
    int arow = nb + w * 16 + l15;
    int arow_c = min(arow, N - 1);

    f32x4 acc[12];
    #pragma unroll
    for (int ct = 0; ct < 12; ++ct) acc[ct] = (f32x4){0.f, 0.f, 0.f, 0.f};

    #pragma unroll
    for (int k0 = 0; k0 < DIN; k0 += 32) {
        const float* ap = x + (size_t)arow_c * DIN + k0 + kg;
        float4 a0 = *(const float4*)ap;
        float4 a1 = *(const float4*)(ap + 4);
        bf16x8 af = pack8(a0, a1);
        #pragma unroll
        for (int ct = 0; ct < 12; ++ct) {
            bf16x8 bf = *(const bf16x8*)(linwt + (size_t)(ct * 16 + l15) * DIN + k0 + kg);
            acc[ct] = __builtin_amdgcn_mfma_f32_16x16x32_bf16(af, bf, acc[ct], 0, 0, 0);
        }
    }

    float asv[12], adv[12];
    #pragma unroll
    for (int ct = 0; ct < 12; ++ct) {
        int c = ct * 16 + l15;
        asv[ct] = att_src[c]; adv[ct] = att_dst[c];
    }

    int rbase = nb + w * 16 + (lane >> 4) * 4;
    #pragma unroll
    for (int j = 0; j < 4; ++j) {
        int r = rbase + j;
        bool ok = r < N;
        float ps0 = 0.f, ps1 = 0.f, ps2 = 0.f, pd0 = 0.f, pd1 = 0.f, pd2 = 0.f;
        #pragma unroll
        for (int ct = 0; ct < 12; ++ct) {
            float v = acc[ct][j];
            float s = v * asv[ct], d = v * adv[ct];
            if (ct < 4)      { ps0 += s; pd0 += d; }
            else if (ct < 8) { ps1 += s; pd1 += d; }
            else             { ps2 += s; pd2 += d; }
        }
        if (ok) {
            unsigned* row32 = (unsigned*)(xsb + (size_t)r * HC);
            #pragma unroll
            for (int ct = 0; ct < 4; ++ct) {
                int c = ct * 16 + l15;
                row32[c] = (unsigned)f2bf(acc[ct][j]) | ((unsigned)f2bf(acc[ct + 4][j]) << 16);
                xsb[(size_t)r * HC + 128 + c] = f2bf(acc[ct + 8][j]);
            }
        }
        #pragma unroll
        for (int o = 1; o < 16; o <<= 1) {
            ps0 += __shfl_xor(ps0, o, 64); pd0 += __shfl_xor(pd0, o, 64);
            ps1 += __shfl_xor(ps1, o, 64); pd1 += __shfl_xor(pd1, o, 64);
            ps2 += __shfl_xor(ps2, o, 64); pd2 += __shfl_xor(pd2, o, 64);
        }
        if (ok && l15 == 0) {
            a_src[r * HH + 0] = ps0 * LOG2E; a_src[r * HH + 1] = ps1 * LOG2E;
            a_src[r * HH + 2] = ps2 * LOG2E;
            a_dst[r * HH + 0] = pd0 * LOG2E; a_dst[r * HH + 1] = pd1 * LOG2E;
            a_dst[r * HH + 2] = pd2 * LOG2E;
        }
    }
}

// ---------- payload fill (CSR order), 16B/edge, a_dst FOLDED IN ----------
__global__ __launch_bounds__(256) void k_fill(const float* __restrict__ ea,
                                              const int* __restrict__ ei,
                                              const float* __restrict__ a_src,
                                              const float* __restrict__ a_dst,
                                              const float* __restrict__ we,
                                              int* __restrict__ cursor,
                                              uint4* __restrict__ payload, int E) {
    int e = blockIdx.x * blockDim.x + threadIdx.x;
    if (e >= E) return;
    int s = ei[e], d = ei[E + e];
    int pos = atomicAdd(&cursor[d], 1);                  // issue early; hide RMW latency
    float attr[ED];
    #pragma unroll
    for (int j = 0; j < ED; ++j) attr[j] = ea[(size_t)e * ED + j];
    float aeh[HH], lp[HH];
    #pragma unroll
    for (int h = 0; h < HH; ++h) {
        float a = 0.f;
        #pragma unroll
        for (int j = 0; j < ED; ++j) a += attr[j] * we[j * HH + h];   // we pre-scaled
        aeh[h] = a;
        lp[h] = a_src[s * HH + h] + a_dst[d * HH + h] + a;             // all pre-scaled
    }
    uint4 pk;
    pk.x = (unsigned)f2bf(lp[0])  | ((unsigned)f2bf(lp[1])  << 16);
    pk.y = (unsigned)f2bf(lp[2])  | ((unsigned)f2bf(aeh[0]) << 16);
    pk.z = (unsigned)f2bf(aeh[1]) | ((unsigned)f2bf(aeh[2]) << 16);
    pk.w = (unsigned)s;
    payload[pos] = pk;
}

// ---------- FUSED: per-dst softmax+gather (16-node tile) -> MLP -> out ----------
__global__ __launch_bounds__(256) void k_gatmlp(const unsigned short* __restrict__ xsb,
                                                const float* __restrict__ a_src,
                                                const float* __restrict__ a_dst,
                                                const int* __restrict__ off,
                                                const int* __restrict__ icnt,
                                                const uint4* __restrict__ payload,
                                                const float* __restrict__ x,
                                                const unsigned short* __restrict__ w1t,
                                                const unsigned short* __restrict__ w2t,
                                                const float* __restrict__ b1p,
                                                const float* __restrict__ g1,
                                                const float* __restrict__ be1,
                                                const float* __restrict__ b2,
                                                const float* __restrict__ g2,
                                                const float* __restrict__ be2,
                                                float* __restrict__ out, int N) {
    __shared__ float4 wbuf[4][64];                 // 4 KB
    __shared__ unsigned short OA[16 * HC];         // 6 KB  oacc tile (bf16, row=HC)
    __shared__ unsigned short H1s[16 * 72];        // 2.25 KB
    __shared__ float red[2][4][16];                // 512 B  LN cross-wave partials
    int lane = threadIdx.x & 63;
    int wid  = threadIdx.x >> 6;
    const unsigned* xs32 = (const unsigned*)xsb;
    unsigned c128ml = 128u - (unsigned)lane;
    int nb16 = blockIdx.x * 16;

    // ======== gather phase: each wave handles 4 nodes serially ========
    #pragma unroll 1
    for (int t = 0; t < 4; ++t) {
        int row = wid * 4 + t;
        int n = nb16 + row;
        if (n < N) {
            int beg = off[n];
            int deg = icnt[n];
            float pden0 = 0.f, pden1 = 0.f, pden2 = 0.f;
            float pae0 = 0.f, pae1 = 0.f, pae2 = 0.f;
            float a0A = 0.f, a1A = 0.f, a2A = 0.f;
            float a0B = 0.f, a1B = 0.f, a2B = 0.f;

            for (int c0 = 0; c0 < deg; c0 += 64) {
                int cn = min(deg - c0, 64);
                float w0 = 0.f, w1 = 0.f, w2 = 0.f;
                int src = 0;
                if (lane < cn) {
                    uint4 p = payload[beg + c0 + lane];
                    w0 = exp2f(leaky(bf_lo(p.x)));
                    w1 = exp2f(leaky(bf_hi(p.x)));
                    w2 = exp2f(leaky(bf_lo(p.y)));
                    pae0 += bf_hi(p.y);
                    pae1 += bf_lo(p.z);
                    pae2 += bf_hi(p.z);
                    pden0 += w0; pden1 += w1; pden2 += w2;
                    src = (int)p.w;
                }
                wbuf[wid][lane] = make_float4(w0, w1, w2, __int_as_float(src));
                int i = 0;
                for (; i + 2 <= cn; i += 2) {
                    float4 ta = wbuf[wid][i];
                    float4 tb = wbuf[wid][i + 1];
                    unsigned ia = __umul24((unsigned)__float_as_int(ta.w), 96u) + lane;
                    unsigned ib = __umul24((unsigned)__float_as_int(tb.w), 96u) + lane;
                    unsigned va = xs32[ia];
                    unsigned vb = xs32[ib];
                    float xa2 = bf2f(xsb[(ia << 1) + c128ml]);
                    float xb2 = bf2f(xsb[(ib << 1) + c128ml]);
                    a0A += ta.x * bf_lo(va); a1A += ta.y * bf_hi(va); a2A += ta.z * xa2;
                    a0B += tb.x * bf_lo(vb); a1B += tb.y * bf_hi(vb); a2B += tb.z * xb2;
                }
                if (i < cn) {
                    float4 ta = wbuf[wid][i];
                    unsigned ia = __umul24((unsigned)__float_as_int(ta.w), 96u) + lane;
                    unsigned va = xs32[ia];
                    a0A += ta.x * bf_lo(va);
                    a1A += ta.y * bf_hi(va);
                    a2A += ta.z * bf2f(xsb[(ia << 1) + c128ml]);
                }
            }

            #pragma unroll
            for (int o = 32; o; o >>= 1) {
                pden0 += __shfl_xor(pden0, o, 64);
                pden1 += __shfl_xor(pden1, o, 64);
                pden2 += __shfl_xor(pden2, o, 64);
                pae0  += __shfl_xor(pae0, o, 64);
                pae1  += __shfl_xor(pae1, o, 64);
                pae2  += __shfl_xor(pae2, o, 64);
            }

            float dc = fmaxf((float)deg, 1.0f);
            float inv_dc = __builtin_amdgcn_rcpf(dc);
            float sl0 = leaky(a_src[n * HH + 0] + a_dst[n * HH + 0] + pae0 * inv_dc);
            float sl1 = leaky(a_src[n * HH + 1] + a_dst[n * HH + 1] + pae1 * inv_dc);
            float sl2 = leaky(a_src[n * HH + 2] + a_dst[n * HH + 2] + pae2 * inv_dc);
            float e0 = exp2f(sl0), e1 = exp2f(sl1), e2 = exp2f(sl2);
            unsigned ian = __umul24((unsigned)n, 96u) + lane;
            unsigned van = xs32[ian];
            float xn2 = bf2f(xsb[(ian << 1) + c128ml]);
            float r0 = __builtin_amdgcn_rcpf(pden0 + e0);
            float r1 = __builtin_amdgcn_rcpf(pden1 + e1);
            float r2 = __builtin_amdgcn_rcpf(pden2 + e2);
            OA[row * HC +       lane] = f2bf((a0A + a0B + e0 * bf_lo(van)) * r0);
            OA[row * HC +  64 + lane] = f2bf((a1A + a1B + e1 * bf_hi(van)) * r1);
            OA[row * HC + 128 + lane] = f2bf((a2A + a2B + e2 * xn2) * r2);
        } else {
            OA[row * HC +       lane] = 0;
            OA[row * HC +  64 + lane] = 0;
            OA[row * HC + 128 + lane] = 0;
        }
    }
    __syncthreads();

    // ======== MLP phase: wave wid owns output cols wid*16..wid*16+15 ========
    int l15 = lane & 15, kg = (lane >> 4) * 8;
    int col = wid * 16 + l15;
    float cb1 = b1p[col], cg1 = g1[col], cbe1 = be1[col];
    float cb2 = b2[col],  cg2 = g2[col], cbe2 = be2[col];

    // GEMM1: [16 x 192] @ [192 x 64(cols of this wave: 16)]
    f32x4 acc = (f32x4){0.f, 0.f, 0.f, 0.f};
    #pragma unroll
    for (int k0 = 0; k0 < HC; k0 += 32) {
        bf16x8 af = *(const bf16x8*)&OA[l15 * HC + k0 + kg];
        bf16x8 bf = *(const bf16x8*)(w1t + (size_t)col * HC + k0 + kg);
        acc = __builtin_amdgcn_mfma_f32_16x16x32_bf16(af, bf, acc, 0, 0, 0);
    }

    int rj0 = (lane >> 4) * 4;
    float y[4], h1v[4];
    #pragma unroll
    for (int j = 0; j < 4; ++j) {
        int r = min(nb16 + rj0 + j, N - 1);
        y[j] = acc[j] + cb1 + x[(size_t)r * DIN + col];
        float s = y[j], q = y[j] * y[j];
        #pragma unroll
        for (int o = 1; o < 16; o <<= 1) {
            s += __shfl_xor(s, o, 64);
            q += __shfl_xor(q, o, 64);
        }
        if (l15 == 0) { red[0][wid][rj0 + j] = s; red[1][wid][rj0 + j] = q; }
    }
    __syncthreads();
    #pragma unroll
    for (int j = 0; j < 4; ++j) {
        int rj = rj0 + j;
        float s = red[0][0][rj] + red[0][1][rj] + red[0][2][rj] + red[0][3][rj];
        float q = red[1][0][rj] + red[1][1][rj] + red[1][2][rj] + red[1][3][rj];
        float m = s * (1.0f / CC);
        float var = q * (1.0f / CC) - m * m;
        float inv = rsqrtf(var + LN_EPS);
        float h = (y[j] - m) * inv * cg1 + cbe1;
        h1v[j] = h;
        H1s[rj * 72 + col] = f2bf(h);
    }
    __syncthreads();

    // GEMM2: [16 x 64] @ [64 x 16]
    f32x4 acc2 = (f32x4){0.f, 0.f, 0.f, 0.f};
    #pragma unroll
    for (int k0 = 0; k0 < CC; k0 += 32) {
        bf16x8 af = *(const bf16x8*)&H1s[l15 * 72 + k0 + kg];
        bf16x8 bf = *(const bf16x8*)(w2t + (size_t)col * CC + k0 + kg);
        acc2 = __builtin_amdgcn_mfma_f32_16x16x32_bf16(af, bf, acc2, 0, 0, 0);
    }

    float z[4];
    #pragma unroll
    for (int j = 0; j < 4; ++j) {
        z[j] = acc2[j] + cb2 + h1v[j];
        float s = z[j], q = z[j] * z[j];
        #pragma unroll
        for (int o = 1; o < 16; o <<= 1) {
            s += __shfl_xor(s, o, 64);
            q += __shfl_xor(q, o, 64);
        }
        if (l15 == 0) { red[0][wid][rj0 + j] = s; red[1][wid][rj0 + j] = q; }
    }
    __syncthreads();
    #pragma unroll
    for (int j = 0; j < 4; ++j) {
        int rj = rj0 + j;
        float s = red[0][0][rj] + red[0][1][rj] + red[0][2][rj] + red[0][3][rj];
        float q = red[1][0][rj] + red[1][1][rj] + red[1][2][rj] + red[1][3][rj];
        float m = s * (1.0f / CC);
        float var = q * (1.0f / CC) - m * m;
        float inv = rsqrtf(var + LN_EPS);
        int r = nb16 + rj;
        if (r < N)
            out[(size_t)r * CC + col] = (z[j] - m) * inv * cg2 + cbe2;
    }
}

extern "C" void kernel_launch(void* const* d_in, const int* in_sizes, int n_in,
                              void* d_out, int out_size, void* d_ws, size_t ws_size,
                              hipStream_t stream) {
    const float* x          = (const float*)d_in[0];
    const float* edge_attr  = (const float*)d_in[1];
    const float* lin_w      = (const float*)d_in[2];
    const float* att_src    = (const float*)d_in[3];
    const float* att_dst    = (const float*)d_in[4];
    const float* lin_edge_w = (const float*)d_in[5];
    const float* att_edge   = (const float*)d_in[6];
    const float* gat_bias   = (const float*)d_in[7];
    const float* w1         = (const float*)d_in[8];
    const float* b1         = (const float*)d_in[9];
    const float* ln1_g      = (const float*)d_in[10];
    const float* ln1_b      = (const float*)d_in[11];
    const float* w2         = (const float*)d_in[12];
    const float* b2         = (const float*)d_in[13];
    const float* ln2_g      = (const float*)d_in[14];
    const float* ln2_b      = (const float*)d_in[15];
    const int*   ei         = (const int*)d_in[16];
    float* out = (float*)d_out;

    const int N = in_sizes[0] / DIN;
    const int E = in_sizes[1] / ED;
    const int nb_scan = (N + 255) / 256;
    const int nbx = (N + 63) / 64;

    char* ws = (char*)d_ws;
    size_t off_b = 0;
    auto alloc = [&](size_t bytes) {
        size_t o = off_b;
        off_b = (off_b + bytes + 255) & ~(size_t)255;
        return o;
    };
    // zeroed region first (single memset)
    int* icnt = (int*)(ws + alloc((size_t)N * 4));
    int* gtot = (int*)(ws + alloc(4));
    size_t zero_bytes = off_b;
    // fully-overwritten region
    unsigned short* xsb = (unsigned short*)(ws + alloc((size_t)N * HC * 2));
    float*  a_srcb  = (float*)(ws + alloc((size_t)N * HH * 4));
    float*  a_dstb  = (float*)(ws + alloc((size_t)N * HH * 4));
    int*    offb    = (int*)(ws + alloc((size_t)N * 4));
    int*    cursor  = (int*)(ws + alloc((size_t)N * 4));
    uint4*  payload = (uint4*)(ws + alloc((size_t)E * 16));
    unsigned short* linwt = (unsigned short*)(ws + alloc((size_t)HC * DIN * 2));
    unsigned short* w1t   = (unsigned short*)(ws + alloc((size_t)DIN * HC * 2));
    unsigned short* w2t   = (unsigned short*)(ws + alloc((size_t)CC * CC * 2));
    float* b1p = (float*)(ws + alloc((size_t)CC * 4));
    float* we  = (float*)(ws + alloc((size_t)ED * HH * 4));
    (void)ws_size; (void)n_in; (void)out_size;

    hipMemsetAsync(d_ws, 0, zero_bytes, stream);

    k_prep_cnt<<<PREP_BLOCKS + (E + 255) / 256, 256, 0, stream>>>(
        lin_w, w1, w2, b1, gat_bias, lin_edge_w, att_edge,
        linwt, w1t, w2t, b1p, we, ei, icnt, E);
    k_xs<<<nbx + nb_scan, 256, 0, stream>>>(x, linwt, att_src, att_dst, xsb,
                                            a_srcb, a_dstb, icnt, gtot, offb, cursor,
                                            N, nbx);
    k_fill<<<(E + 255) / 256, 256, 0, stream>>>(edge_attr, ei, a_srcb, a_dstb, we, cursor,
                                                payload, E);
    k_gatmlp<<<(N + 15) / 16, 256, 0, stream>>>(xsb, a_srcb, a_dstb, offb, icnt, payload,
                                                x, w1t, w2t, b1p, ln1_g, ln1_b,
                                                b2, ln2_g, ln2_b, out, N);
}